// Round 1
// baseline (3984.567 us; speedup 1.0000x reference)
//
#include <hip/hip_runtime.h>
#include <hip/hip_runtime_api.h>

#define NNODES 50000
#define NEDGES 800000
#define EETOT  850000   // edges + self loops
#define GG 32
#define KCUR 16
#define FIN 128
#define HIDN 64
#define NHEADS 4
#define F1 256          // NHEADS*HIDN

// ---- monotone float<->uint key for atomicMax on floats ----
__device__ __forceinline__ unsigned fkey(float f) {
    unsigned u = __float_as_uint(f);
    return (u & 0x80000000u) ? ~u : (u | 0x80000000u);
}
__device__ __forceinline__ float fdec(unsigned k) {
    unsigned u = (k & 0x80000000u) ? (k & 0x7fffffffu) : ~k;
    return __uint_as_float(u);
}
__device__ __forceinline__ float lrelu(float x) { return x > 0.f ? x : 0.2f * x; }

// ---------------- tiled fp32 GEMM: C[M,NC] = A[M,K] @ B[K,NC] ----------------
__global__ __launch_bounds__(256)
void gemm_tiled(const float* __restrict__ A, const float* __restrict__ B,
                float* __restrict__ C, int M, int K, int NC)
{
    __shared__ float As[16][64];
    __shared__ float Bs[16][64];
    const int tid = threadIdx.x;
    const int tx = tid & 15, ty = tid >> 4;
    const int i0 = blockIdx.x * 64;
    const int j0 = blockIdx.y * 64;
    const int lrow = tid >> 2;          // 0..63
    const int lk4  = (tid & 3) << 2;    // 0,4,8,12
    const int bkk  = tid >> 4;          // 0..15
    const int bc4  = (tid & 15) << 2;   // 0..60
    float acc[4][4];
#pragma unroll
    for (int r = 0; r < 4; r++)
#pragma unroll
        for (int c = 0; c < 4; c++) acc[r][c] = 0.f;

    for (int k0 = 0; k0 < K; k0 += 16) {
        float4 av = make_float4(0.f, 0.f, 0.f, 0.f);
        int ar = i0 + lrow;
        if (ar < M) av = *(const float4*)(A + (size_t)ar * K + k0 + lk4);
        As[lk4 + 0][lrow] = av.x;
        As[lk4 + 1][lrow] = av.y;
        As[lk4 + 2][lrow] = av.z;
        As[lk4 + 3][lrow] = av.w;
        *(float4*)&Bs[bkk][bc4] = *(const float4*)(B + (size_t)(k0 + bkk) * NC + j0 + bc4);
        __syncthreads();
#pragma unroll
        for (int kk = 0; kk < 16; kk++) {
            float a[4], b[4];
#pragma unroll
            for (int r = 0; r < 4; r++) a[r] = As[kk][ty * 4 + r];
#pragma unroll
            for (int c = 0; c < 4; c++) b[c] = Bs[kk][tx * 4 + c];
#pragma unroll
            for (int r = 0; r < 4; r++)
#pragma unroll
                for (int c = 0; c < 4; c++) acc[r][c] = fmaf(a[r], b[c], acc[r][c]);
        }
        __syncthreads();
    }
#pragma unroll
    for (int r = 0; r < 4; r++) {
        int row = i0 + ty * 4 + r;
        if (row < M) {
            float4 v = make_float4(acc[r][0], acc[r][1], acc[r][2], acc[r][3]);
            *(float4*)(C + (size_t)row * NC + j0 + tx * 4) = v;
        }
    }
}

// ---------------- layer-1 attention dot products a_s[n,h], a_d[n,h] ----------------
__global__ __launch_bounds__(256)
void attdots1(const float* __restrict__ h1, const float* __restrict__ asw,
              const float* __restrict__ adw, float* __restrict__ as1, float* __restrict__ ad1)
{
    int gid = blockIdx.x * 256 + threadIdx.x;
    if (gid >= NNODES * NHEADS) return;
    int n = gid >> 2, h = gid & 3;
    const float4* hv = (const float4*)(h1 + (size_t)n * F1 + h * HIDN);
    const float4* sw = (const float4*)(asw + h * HIDN);
    const float4* dw = (const float4*)(adw + h * HIDN);
    float s = 0.f, d = 0.f;
#pragma unroll 4
    for (int i = 0; i < 16; i++) {
        float4 hh = hv[i], ss = sw[i], dd = dw[i];
        s += hh.x * ss.x + hh.y * ss.y + hh.z * ss.z + hh.w * ss.w;
        d += hh.x * dd.x + hh.y * dd.y + hh.z * dd.z + hh.w * dd.w;
    }
    as1[gid] = s; ad1[gid] = d;
}

// ---------------- layer-1 segment max (per dst, per head) ----------------
__global__ __launch_bounds__(256)
void max1_k(const int* __restrict__ src, const int* __restrict__ dst,
            const float* __restrict__ as1, const float* __restrict__ ad1,
            unsigned* __restrict__ m1key)
{
    int gid = blockIdx.x * 256 + threadIdx.x;
    if (gid >= EETOT * NHEADS) return;
    int e = gid >> 2, h = gid & 3;
    int s, d;
    if (e < NEDGES) { s = src[e]; d = dst[e]; } else { s = d = e - NEDGES; }
    float v = lrelu(as1[s * 4 + h] + ad1[d * 4 + h]);
    atomicMax(&m1key[d * 4 + h], fkey(v));
}

// ---------------- layer-1 aggregation: one wave per edge, 4 ch per lane ----------------
__global__ __launch_bounds__(256)
void agg1_k(const int* __restrict__ src, const int* __restrict__ dst,
            const float* __restrict__ as1, const float* __restrict__ ad1,
            const unsigned* __restrict__ m1key, const float* __restrict__ h1,
            float* __restrict__ agg1, float* __restrict__ denom1)
{
    long long gid = (long long)blockIdx.x * 256 + threadIdx.x;
    int e = (int)(gid >> 6);
    int lane = (int)(gid & 63);
    if (e >= EETOT) return;
    int s, d;
    if (e < NEDGES) { s = src[e]; d = dst[e]; } else { s = d = e - NEDGES; }
    int c0 = lane << 2;       // 0..252
    int h = c0 >> 6;          // head
    float el = lrelu(as1[s * 4 + h] + ad1[d * 4 + h]);
    float m = fdec(m1key[d * 4 + h]);
    float ex = __expf(el - m);
    if ((lane & 15) == 0) atomicAdd(&denom1[d * 4 + h], ex);
    float4 hv = *(const float4*)(h1 + (size_t)s * F1 + c0);
    float* o = agg1 + (size_t)d * F1 + c0;
    atomicAdd(o + 0, ex * hv.x);
    atomicAdd(o + 1, ex * hv.y);
    atomicAdd(o + 2, ex * hv.z);
    atomicAdd(o + 3, ex * hv.w);
}

// ---------------- layer-1 finalize: h1r = relu(agg/denom + b1), in place ----------------
__global__ __launch_bounds__(256)
void fin1_k(float* __restrict__ agg1, const float* __restrict__ denom1,
            const float* __restrict__ b1)
{
    int gid = blockIdx.x * 256 + threadIdx.x;
    if (gid >= NNODES * 64) return;
    int n = gid >> 6, j0 = (gid & 63) << 2;
    float den = denom1[n * 4 + (j0 >> 6)];
    float4 v = *(float4*)(agg1 + (size_t)n * F1 + j0);
    float4 bb = *(const float4*)(b1 + j0);
    v.x = fmaxf(v.x / den + bb.x, 0.f);
    v.y = fmaxf(v.y / den + bb.y, 0.f);
    v.z = fmaxf(v.z / den + bb.z, 0.f);
    v.w = fmaxf(v.w / den + bb.w, 0.f);
    *(float4*)(agg1 + (size_t)n * F1 + j0) = v;
}

// ---------------- layer-2 attention dots ----------------
__global__ __launch_bounds__(256)
void attdots2(const float* __restrict__ h2, const float* __restrict__ asw,
              const float* __restrict__ adw, float* __restrict__ as2, float* __restrict__ ad2)
{
    int n = blockIdx.x * 256 + threadIdx.x;
    if (n >= NNODES) return;
    const float4* hv = (const float4*)(h2 + (size_t)n * HIDN);
    const float4* sw = (const float4*)asw;
    const float4* dw = (const float4*)adw;
    float s = 0.f, d = 0.f;
#pragma unroll 4
    for (int i = 0; i < 16; i++) {
        float4 hh = hv[i], ss = sw[i], dd = dw[i];
        s += hh.x * ss.x + hh.y * ss.y + hh.z * ss.z + hh.w * ss.w;
        d += hh.x * dd.x + hh.y * dd.y + hh.z * dd.z + hh.w * dd.w;
    }
    as2[n] = s; ad2[n] = d;
}

__global__ __launch_bounds__(256)
void max2_k(const int* __restrict__ src, const int* __restrict__ dst,
            const float* __restrict__ as2, const float* __restrict__ ad2,
            unsigned* __restrict__ m2key)
{
    int e = blockIdx.x * 256 + threadIdx.x;
    if (e >= EETOT) return;
    int s, d;
    if (e < NEDGES) { s = src[e]; d = dst[e]; } else { s = d = e - NEDGES; }
    atomicMax(&m2key[d], fkey(lrelu(as2[s] + ad2[d])));
}

__global__ __launch_bounds__(256)
void agg2_k(const int* __restrict__ src, const int* __restrict__ dst,
            const float* __restrict__ as2, const float* __restrict__ ad2,
            const unsigned* __restrict__ m2key, const float* __restrict__ h2,
            float* __restrict__ agg2, float* __restrict__ denom2)
{
    long long gid = (long long)blockIdx.x * 256 + threadIdx.x;
    int e = (int)(gid >> 4);
    int q = (int)(gid & 15);
    if (e >= EETOT) return;
    int s, d;
    if (e < NEDGES) { s = src[e]; d = dst[e]; } else { s = d = e - NEDGES; }
    float el = lrelu(as2[s] + ad2[d]);
    float ex = __expf(el - fdec(m2key[d]));
    if (q == 0) atomicAdd(&denom2[d], ex);
    int c0 = q << 2;
    float4 hv = *(const float4*)(h2 + (size_t)s * HIDN + c0);
    float* o = agg2 + (size_t)d * HIDN + c0;
    atomicAdd(o + 0, ex * hv.x);
    atomicAdd(o + 1, ex * hv.y);
    atomicAdd(o + 2, ex * hv.z);
    atomicAdd(o + 3, ex * hv.w);
}

// ---------------- layer-2 finalize: hf = agg/denom + b2, in place ----------------
__global__ __launch_bounds__(256)
void fin2_k(float* __restrict__ agg2, const float* __restrict__ denom2,
            const float* __restrict__ b2)
{
    int gid = blockIdx.x * 256 + threadIdx.x;
    if (gid >= NNODES * 16) return;
    int n = gid >> 4, c0 = (gid & 15) << 2;
    float den = denom2[n];
    float4 v = *(float4*)(agg2 + (size_t)n * HIDN + c0);
    float4 bb = *(const float4*)(b2 + c0);
    v.x = v.x / den + bb.x;
    v.y = v.y / den + bb.y;
    v.z = v.z / den + bb.z;
    v.w = v.w / den + bb.w;
    *(float4*)(agg2 + (size_t)n * HIDN + c0) = v;
}

// ---------------- node scores = tanh(hf @ action_w + action_b) ----------------
__global__ __launch_bounds__(256)
void scores_k(const float* __restrict__ hf, const float* __restrict__ aw,
              const float* __restrict__ ab, float* __restrict__ scores)
{
    int n = blockIdx.x * 256 + threadIdx.x;
    if (n >= NNODES) return;
    const float4* hv = (const float4*)(hf + (size_t)n * HIDN);
    const float4* wv = (const float4*)aw;
    float s = 0.f;
#pragma unroll 4
    for (int i = 0; i < 16; i++) {
        float4 hh = hv[i], ww = wv[i];
        s += hh.x * ww.x + hh.y * ww.y + hh.z * ww.z + hh.w * ww.w;
    }
    scores[n] = tanhf(s + ab[0]);
}

// ---------------- per-graph context pooling + stop score ----------------
__global__ __launch_bounds__(64)
void ctx_k(const float* __restrict__ hf, const int* __restrict__ cur_nodes,
           const int* __restrict__ cur_counts, const float* __restrict__ sw,
           const float* __restrict__ sb, float* __restrict__ stop_scores,
           unsigned* __restrict__ gmaxkey)
{
    int g = blockIdx.x;
    int c = threadIdx.x;
    int cnt = cur_counts[g];
    float s = 0.f;
    for (int k = 0; k < KCUR; k++) {
        if (k < cnt) {
            int node = cur_nodes[g * KCUR + k];
            s += hf[(size_t)node * HIDN + c];
        }
    }
    float ctx = s / (float)(cnt > 1 ? cnt : 1);
    float p = ctx * sw[c];
    for (int o = 32; o; o >>= 1) p += __shfl_down(p, o);
    if (c == 0) {
        float st = tanhf(p + sb[0]);
        stop_scores[g] = st;
        atomicMax(&gmaxkey[g], fkey(st));
    }
}

// ---------------- per-graph masked max over node scores ----------------
__global__ __launch_bounds__(256)
void redmax_k(const float* __restrict__ scores, const int* __restrict__ masks,
              unsigned* __restrict__ gmaxkey)
{
    __shared__ float lds[4];
    int g = blockIdx.y;
    float lm = -3.0e38f;
    for (int n = blockIdx.x * 256 + threadIdx.x; n < NNODES; n += gridDim.x * 256)
        if (masks[(size_t)g * NNODES + n]) lm = fmaxf(lm, scores[n]);
    for (int o = 32; o; o >>= 1) lm = fmaxf(lm, __shfl_down(lm, o));
    if ((threadIdx.x & 63) == 0) lds[threadIdx.x >> 6] = lm;
    __syncthreads();
    if (threadIdx.x == 0) {
        lm = fmaxf(fmaxf(lds[0], lds[1]), fmaxf(lds[2], lds[3]));
        atomicMax(&gmaxkey[g], fkey(lm));
    }
}

// ---------------- per-graph masked exp-sum ----------------
__global__ __launch_bounds__(256)
void redsum_k(const float* __restrict__ scores, const int* __restrict__ masks,
              const unsigned* __restrict__ gmaxkey, const float* __restrict__ stop_scores,
              float* __restrict__ gsum)
{
    __shared__ float lds[4];
    int g = blockIdx.y;
    float m = fdec(gmaxkey[g]);
    float ls = 0.f;
    for (int n = blockIdx.x * 256 + threadIdx.x; n < NNODES; n += gridDim.x * 256)
        if (masks[(size_t)g * NNODES + n]) ls += __expf(scores[n] - m);
    for (int o = 32; o; o >>= 1) ls += __shfl_down(ls, o);
    if ((threadIdx.x & 63) == 0) lds[threadIdx.x >> 6] = ls;
    __syncthreads();
    if (threadIdx.x == 0) {
        ls = lds[0] + lds[1] + lds[2] + lds[3];
        if (blockIdx.x == 0) ls += __expf(stop_scores[g] - m);
        atomicAdd(&gsum[g], ls);
    }
}

// ---------------- final probability write ----------------
__global__ __launch_bounds__(256)
void write_k(const float* __restrict__ scores, const int* __restrict__ masks,
             const unsigned* __restrict__ gmaxkey, const float* __restrict__ gsum,
             const float* __restrict__ stop_scores, const int* __restrict__ cur_counts,
             float* __restrict__ out)
{
    int g = blockIdx.y;
    int j = blockIdx.x * 256 + threadIdx.x;
    if (j > NNODES) return;
    float v;
    if (cur_counts[g] == 0) {
        v = (j == NNODES) ? 1.f : 0.f;
    } else {
        float m = fdec(gmaxkey[g]);
        float Z = gsum[g];
        if (j == NNODES) v = __expf(stop_scores[g] - m) / Z;
        else v = masks[(size_t)g * NNODES + j] ? __expf(scores[j] - m) / Z : 0.f;
    }
    out[(size_t)g * (NNODES + 1) + j] = v;
}

extern "C" void kernel_launch(void* const* d_in, const int* in_sizes, int n_in,
                              void* d_out, int out_size, void* d_ws, size_t ws_size,
                              hipStream_t stream) {
    const float* x        = (const float*)d_in[0];
    const int* ei         = (const int*)d_in[1];
    const int* cur_nodes  = (const int*)d_in[2];
    const int* cur_counts = (const int*)d_in[3];
    const int* masks      = (const int*)d_in[4];
    const float* W1       = (const float*)d_in[5];
    const float* att_s1   = (const float*)d_in[6];
    const float* att_d1   = (const float*)d_in[7];
    const float* b1       = (const float*)d_in[8];
    const float* W2       = (const float*)d_in[9];
    const float* att_s2   = (const float*)d_in[10];
    const float* att_d2   = (const float*)d_in[11];
    const float* b2       = (const float*)d_in[12];
    const float* action_w = (const float*)d_in[13];
    const float* action_b = (const float*)d_in[14];
    const float* stop_w   = (const float*)d_in[15];
    const float* stop_b   = (const float*)d_in[16];
    float* out = (float*)d_out;

    const int* srcp = ei;
    const int* dstp = ei + NEDGES;

    // ---- workspace layout ----
    // zero region (memset each call):
    float* agg1 = (float*)d_ws;                              // N*256
    float* agg2 = agg1 + (size_t)NNODES * F1;                // N*64
    unsigned* m1key = (unsigned*)(agg2 + (size_t)NNODES * HIDN); // N*4
    float* denom1 = (float*)(m1key + (size_t)NNODES * 4);    // N*4
    unsigned* m2key = (unsigned*)(denom1 + (size_t)NNODES * 4); // N
    float* denom2 = (float*)(m2key + NNODES);                // N
    unsigned* gmaxkey = (unsigned*)(denom2 + NNODES);        // G
    float* gsum = (float*)(gmaxkey + GG);                    // G
    float* zend = gsum + GG;
    size_t zbytes = (char*)zend - (char*)d_ws;
    // non-zero region:
    float* h1 = zend;                                        // N*256
    float* as1 = h1 + (size_t)NNODES * F1;                   // N*4
    float* ad1 = as1 + (size_t)NNODES * 4;                   // N*4
    float* h2 = ad1 + (size_t)NNODES * 4;                    // N*64
    float* as2 = h2 + (size_t)NNODES * HIDN;                 // N
    float* ad2 = as2 + NNODES;                               // N
    float* scores = ad2 + NNODES;                            // N
    float* stop_scores = scores + NNODES;                    // G
    size_t total = (char*)(stop_scores + GG) - (char*)d_ws;
    if (total > ws_size) return;  // insufficient workspace -> clean failure

    auto cdiv = [](long long a, long long b) { return (int)((a + b - 1) / b); };

    hipMemsetAsync(d_ws, 0, zbytes, stream);

    // layer 1
    gemm_tiled<<<dim3(cdiv(NNODES, 64), F1 / 64), 256, 0, stream>>>(x, W1, h1, NNODES, FIN, F1);
    attdots1<<<cdiv((long long)NNODES * NHEADS, 256), 256, 0, stream>>>(h1, att_s1, att_d1, as1, ad1);
    max1_k<<<cdiv((long long)EETOT * NHEADS, 256), 256, 0, stream>>>(srcp, dstp, as1, ad1, m1key);
    agg1_k<<<cdiv((long long)EETOT * 64, 256), 256, 0, stream>>>(srcp, dstp, as1, ad1, m1key, h1, agg1, denom1);
    fin1_k<<<cdiv((long long)NNODES * 64, 256), 256, 0, stream>>>(agg1, denom1, b1);

    // layer 2 (input = agg1, now holding relu'd layer-1 output)
    gemm_tiled<<<dim3(cdiv(NNODES, 64), HIDN / 64), 256, 0, stream>>>(agg1, W2, h2, NNODES, F1, HIDN);
    attdots2<<<cdiv(NNODES, 256), 256, 0, stream>>>(h2, att_s2, att_d2, as2, ad2);
    max2_k<<<cdiv(EETOT, 256), 256, 0, stream>>>(srcp, dstp, as2, ad2, m2key);
    agg2_k<<<cdiv((long long)EETOT * 16, 256), 256, 0, stream>>>(srcp, dstp, as2, ad2, m2key, h2, agg2, denom2);
    fin2_k<<<cdiv((long long)NNODES * 16, 256), 256, 0, stream>>>(agg2, denom2, b2);

    // heads
    scores_k<<<cdiv(NNODES, 256), 256, 0, stream>>>(agg2, action_w, action_b, scores);
    ctx_k<<<GG, 64, 0, stream>>>(agg2, cur_nodes, cur_counts, stop_w, stop_b, stop_scores, gmaxkey);
    redmax_k<<<dim3(64, GG), 256, 0, stream>>>(scores, masks, gmaxkey);
    redsum_k<<<dim3(64, GG), 256, 0, stream>>>(scores, masks, gmaxkey, stop_scores, gsum);
    write_k<<<dim3(cdiv(NNODES + 1, 256), GG), 256, 0, stream>>>(scores, masks, gmaxkey, gsum,
                                                                 stop_scores, cur_counts, out);
}

// Round 2
// 683.099 us; speedup vs baseline: 5.8331x; 5.8331x over previous
//
#include <hip/hip_runtime.h>
#include <hip/hip_runtime_api.h>

#define NNODES 50000
#define NEDGES 800000
#define GG 32
#define KCUR 16
#define FIN 128
#define HIDN 64
#define NHEADS 4
#define F1 256          // NHEADS*HIDN

// ---- monotone float<->uint key for atomicMax on floats ----
__device__ __forceinline__ unsigned fkey(float f) {
    unsigned u = __float_as_uint(f);
    return (u & 0x80000000u) ? ~u : (u | 0x80000000u);
}
__device__ __forceinline__ float fdec(unsigned k) {
    unsigned u = (k & 0x80000000u) ? (k & 0x7fffffffu) : ~k;
    return __uint_as_float(u);
}
__device__ __forceinline__ float lrelu(float x) { return x > 0.f ? x : 0.2f * x; }

// ---------------- tiled fp32 GEMM: C[M,NC] = A[M,K] @ B[K,NC] ----------------
__global__ __launch_bounds__(256)
void gemm_tiled(const float* __restrict__ A, const float* __restrict__ B,
                float* __restrict__ C, int M, int K, int NC)
{
    __shared__ float As[16][64];
    __shared__ float Bs[16][64];
    const int tid = threadIdx.x;
    const int tx = tid & 15, ty = tid >> 4;
    const int i0 = blockIdx.x * 64;
    const int j0 = blockIdx.y * 64;
    const int lrow = tid >> 2;          // 0..63
    const int lk4  = (tid & 3) << 2;    // 0,4,8,12
    const int bkk  = tid >> 4;          // 0..15
    const int bc4  = (tid & 15) << 2;   // 0..60
    float acc[4][4];
#pragma unroll
    for (int r = 0; r < 4; r++)
#pragma unroll
        for (int c = 0; c < 4; c++) acc[r][c] = 0.f;

    for (int k0 = 0; k0 < K; k0 += 16) {
        float4 av = make_float4(0.f, 0.f, 0.f, 0.f);
        int ar = i0 + lrow;
        if (ar < M) av = *(const float4*)(A + (size_t)ar * K + k0 + lk4);
        As[lk4 + 0][lrow] = av.x;
        As[lk4 + 1][lrow] = av.y;
        As[lk4 + 2][lrow] = av.z;
        As[lk4 + 3][lrow] = av.w;
        *(float4*)&Bs[bkk][bc4] = *(const float4*)(B + (size_t)(k0 + bkk) * NC + j0 + bc4);
        __syncthreads();
#pragma unroll
        for (int kk = 0; kk < 16; kk++) {
            float a[4], b[4];
#pragma unroll
            for (int r = 0; r < 4; r++) a[r] = As[kk][ty * 4 + r];
#pragma unroll
            for (int c = 0; c < 4; c++) b[c] = Bs[kk][tx * 4 + c];
#pragma unroll
            for (int r = 0; r < 4; r++)
#pragma unroll
                for (int c = 0; c < 4; c++) acc[r][c] = fmaf(a[r], b[c], acc[r][c]);
        }
        __syncthreads();
    }
#pragma unroll
    for (int r = 0; r < 4; r++) {
        int row = i0 + ty * 4 + r;
        if (row < M) {
            float4 v = make_float4(acc[r][0], acc[r][1], acc[r][2], acc[r][3]);
            *(float4*)(C + (size_t)row * NC + j0 + tx * 4) = v;
        }
    }
}

// ---------------- CSR build ----------------
__global__ __launch_bounds__(256)
void hist_k(const int* __restrict__ dst, int* __restrict__ deg)
{
    int e = blockIdx.x * 256 + threadIdx.x;
    if (e >= NEDGES) return;
    atomicAdd(&deg[dst[e]], 1);
}

__global__ __launch_bounds__(1024)
void scan_k(const int* __restrict__ deg, int* __restrict__ rowptr, int* __restrict__ cursor)
{
    __shared__ int wsum[16], woff[16];
    __shared__ int running;
    int tid = threadIdx.x, lane = tid & 63, wid = tid >> 6;
    if (tid == 0) running = 0;
    __syncthreads();
    for (int base = 0; base < NNODES; base += 1024) {
        int i = base + tid;
        int v = (i < NNODES) ? deg[i] : 0;
        int x = v;
#pragma unroll
        for (int o = 1; o < 64; o <<= 1) {
            int y = __shfl_up(x, o);
            if (lane >= o) x += y;
        }
        if (lane == 63) wsum[wid] = x;
        __syncthreads();
        if (tid == 0) {
            int t = 0;
#pragma unroll
            for (int w = 0; w < 16; w++) { woff[w] = t; t += wsum[w]; }
        }
        __syncthreads();
        int excl = running + woff[wid] + (x - v);
        if (i < NNODES) { rowptr[i] = excl; cursor[i] = excl; }
        __syncthreads();
        if (tid == 0) running += woff[15] + wsum[15];
        __syncthreads();
    }
    if (threadIdx.x == 0) rowptr[NNODES] = running;
}

__global__ __launch_bounds__(256)
void scatter_k(const int* __restrict__ src, const int* __restrict__ dst,
               int* __restrict__ cursor, int* __restrict__ csr)
{
    int e = blockIdx.x * 256 + threadIdx.x;
    if (e >= NEDGES) return;
    int d = dst[e];
    int pos = atomicAdd(&cursor[d], 1);
    csr[pos] = src[e];
}

// ---------------- layer-1 attention dot products ----------------
__global__ __launch_bounds__(256)
void attdots1(const float* __restrict__ h1, const float* __restrict__ asw,
              const float* __restrict__ adw, float* __restrict__ as1, float* __restrict__ ad1)
{
    int gid = blockIdx.x * 256 + threadIdx.x;
    if (gid >= NNODES * NHEADS) return;
    int n = gid >> 2, h = gid & 3;
    const float4* hv = (const float4*)(h1 + (size_t)n * F1 + h * HIDN);
    const float4* sw = (const float4*)(asw + h * HIDN);
    const float4* dw = (const float4*)(adw + h * HIDN);
    float s = 0.f, d = 0.f;
#pragma unroll 4
    for (int i = 0; i < 16; i++) {
        float4 hh = hv[i], ss = sw[i], dd = dw[i];
        s += hh.x * ss.x + hh.y * ss.y + hh.z * ss.z + hh.w * ss.w;
        d += hh.x * dd.x + hh.y * dd.y + hh.z * dd.z + hh.w * dd.w;
    }
    as1[gid] = s; ad1[gid] = d;
}

// ---------------- layer-1 gather aggregation: one wave per dst ----------------
// lane -> 4 channels (c0 = lane*4), head h = lane>>4. Fused segment-softmax +
// weighted sum + bias + relu. Self loop included. One 1KB coalesced write/node.
__global__ __launch_bounds__(256)
void gagg1(const int* __restrict__ rowptr, const int* __restrict__ csr,
           const float* __restrict__ as1, const float* __restrict__ ad1,
           const float* __restrict__ h1, const float* __restrict__ b1,
           float* __restrict__ outp)
{
    int wid = threadIdx.x >> 6, lane = threadIdx.x & 63;
    int d = blockIdx.x * 4 + wid;
    if (d >= NNODES) return;
    int beg = rowptr[d], end = rowptr[d + 1];
    int h = lane >> 4, c0 = lane << 2;
    float adh = ad1[d * 4 + h];
    float selfE = lrelu(as1[d * 4 + h] + adh);
    float m = selfE;
    for (int e = beg; e < end; e++) {
        int s = csr[e];
        m = fmaxf(m, lrelu(as1[s * 4 + h] + adh));
    }
    float exs = __expf(selfE - m);
    float den = exs;
    float4 hv = *(const float4*)(h1 + (size_t)d * F1 + c0);
    float4 acc = make_float4(exs * hv.x, exs * hv.y, exs * hv.z, exs * hv.w);
    for (int e = beg; e < end; e++) {
        int s = csr[e];
        float ex = __expf(lrelu(as1[s * 4 + h] + adh) - m);
        den += ex;
        float4 sv = *(const float4*)(h1 + (size_t)s * F1 + c0);
        acc.x = fmaf(ex, sv.x, acc.x);
        acc.y = fmaf(ex, sv.y, acc.y);
        acc.z = fmaf(ex, sv.z, acc.z);
        acc.w = fmaf(ex, sv.w, acc.w);
    }
    float4 bb = *(const float4*)(b1 + c0);
    float rden = 1.f / den;
    float4 o;
    o.x = fmaxf(fmaf(acc.x, rden, bb.x), 0.f);
    o.y = fmaxf(fmaf(acc.y, rden, bb.y), 0.f);
    o.z = fmaxf(fmaf(acc.z, rden, bb.z), 0.f);
    o.w = fmaxf(fmaf(acc.w, rden, bb.w), 0.f);
    *(float4*)(outp + (size_t)d * F1 + c0) = o;
}

// ---------------- layer-2 attention dots ----------------
__global__ __launch_bounds__(256)
void attdots2(const float* __restrict__ h2, const float* __restrict__ asw,
              const float* __restrict__ adw, float* __restrict__ as2, float* __restrict__ ad2)
{
    int n = blockIdx.x * 256 + threadIdx.x;
    if (n >= NNODES) return;
    const float4* hv = (const float4*)(h2 + (size_t)n * HIDN);
    const float4* sw = (const float4*)asw;
    const float4* dw = (const float4*)adw;
    float s = 0.f, d = 0.f;
#pragma unroll 4
    for (int i = 0; i < 16; i++) {
        float4 hh = hv[i], ss = sw[i], dd = dw[i];
        s += hh.x * ss.x + hh.y * ss.y + hh.z * ss.z + hh.w * ss.w;
        d += hh.x * dd.x + hh.y * dd.y + hh.z * dd.z + hh.w * dd.w;
    }
    as2[n] = s; ad2[n] = d;
}

// ---------------- layer-2 gather aggregation: one wave per dst, lane=channel ----
__global__ __launch_bounds__(256)
void gagg2(const int* __restrict__ rowptr, const int* __restrict__ csr,
           const float* __restrict__ as2, const float* __restrict__ ad2,
           const float* __restrict__ h2, const float* __restrict__ b2,
           float* __restrict__ outp)
{
    int wid = threadIdx.x >> 6, lane = threadIdx.x & 63;
    int d = blockIdx.x * 4 + wid;
    if (d >= NNODES) return;
    int beg = rowptr[d], end = rowptr[d + 1];
    float ads = ad2[d];
    float selfE = lrelu(as2[d] + ads);
    float m = selfE;
    for (int e = beg; e < end; e++) {
        int s = csr[e];
        m = fmaxf(m, lrelu(as2[s] + ads));
    }
    float exs = __expf(selfE - m);
    float den = exs;
    float acc = exs * h2[(size_t)d * HIDN + lane];
    for (int e = beg; e < end; e++) {
        int s = csr[e];
        float ex = __expf(lrelu(as2[s] + ads) - m);
        den += ex;
        acc = fmaf(ex, h2[(size_t)s * HIDN + lane], acc);
    }
    outp[(size_t)d * HIDN + lane] = acc / den + b2[lane];
}

// ---------------- node scores = tanh(hf @ action_w + action_b) ----------------
__global__ __launch_bounds__(256)
void scores_k(const float* __restrict__ hf, const float* __restrict__ aw,
              const float* __restrict__ ab, float* __restrict__ scores)
{
    int n = blockIdx.x * 256 + threadIdx.x;
    if (n >= NNODES) return;
    const float4* hv = (const float4*)(hf + (size_t)n * HIDN);
    const float4* wv = (const float4*)aw;
    float s = 0.f;
#pragma unroll 4
    for (int i = 0; i < 16; i++) {
        float4 hh = hv[i], ww = wv[i];
        s += hh.x * ww.x + hh.y * ww.y + hh.z * ww.z + hh.w * ww.w;
    }
    scores[n] = tanhf(s + ab[0]);
}

// ---------------- per-graph context pooling + stop score ----------------
__global__ __launch_bounds__(64)
void ctx_k(const float* __restrict__ hf, const int* __restrict__ cur_nodes,
           const int* __restrict__ cur_counts, const float* __restrict__ sw,
           const float* __restrict__ sb, float* __restrict__ stop_scores,
           unsigned* __restrict__ gmaxkey)
{
    int g = blockIdx.x;
    int c = threadIdx.x;
    int cnt = cur_counts[g];
    float s = 0.f;
    for (int k = 0; k < KCUR; k++) {
        if (k < cnt) {
            int node = cur_nodes[g * KCUR + k];
            s += hf[(size_t)node * HIDN + c];
        }
    }
    float ctx = s / (float)(cnt > 1 ? cnt : 1);
    float p = ctx * sw[c];
    for (int o = 32; o; o >>= 1) p += __shfl_down(p, o);
    if (c == 0) {
        float st = tanhf(p + sb[0]);
        stop_scores[g] = st;
        atomicMax(&gmaxkey[g], fkey(st));
    }
}

// ---------------- per-graph masked max over node scores ----------------
__global__ __launch_bounds__(256)
void redmax_k(const float* __restrict__ scores, const int* __restrict__ masks,
              unsigned* __restrict__ gmaxkey)
{
    __shared__ float lds[4];
    int g = blockIdx.y;
    float lm = -3.0e38f;
    for (int n = blockIdx.x * 256 + threadIdx.x; n < NNODES; n += gridDim.x * 256)
        if (masks[(size_t)g * NNODES + n]) lm = fmaxf(lm, scores[n]);
    for (int o = 32; o; o >>= 1) lm = fmaxf(lm, __shfl_down(lm, o));
    if ((threadIdx.x & 63) == 0) lds[threadIdx.x >> 6] = lm;
    __syncthreads();
    if (threadIdx.x == 0) {
        lm = fmaxf(fmaxf(lds[0], lds[1]), fmaxf(lds[2], lds[3]));
        atomicMax(&gmaxkey[g], fkey(lm));
    }
}

// ---------------- per-graph masked exp-sum ----------------
__global__ __launch_bounds__(256)
void redsum_k(const float* __restrict__ scores, const int* __restrict__ masks,
              const unsigned* __restrict__ gmaxkey, const float* __restrict__ stop_scores,
              float* __restrict__ gsum)
{
    __shared__ float lds[4];
    int g = blockIdx.y;
    float m = fdec(gmaxkey[g]);
    float ls = 0.f;
    for (int n = blockIdx.x * 256 + threadIdx.x; n < NNODES; n += gridDim.x * 256)
        if (masks[(size_t)g * NNODES + n]) ls += __expf(scores[n] - m);
    for (int o = 32; o; o >>= 1) ls += __shfl_down(ls, o);
    if ((threadIdx.x & 63) == 0) lds[threadIdx.x >> 6] = ls;
    __syncthreads();
    if (threadIdx.x == 0) {
        ls = lds[0] + lds[1] + lds[2] + lds[3];
        if (blockIdx.x == 0) ls += __expf(stop_scores[g] - m);
        atomicAdd(&gsum[g], ls);
    }
}

// ---------------- final probability write ----------------
__global__ __launch_bounds__(256)
void write_k(const float* __restrict__ scores, const int* __restrict__ masks,
             const unsigned* __restrict__ gmaxkey, const float* __restrict__ gsum,
             const float* __restrict__ stop_scores, const int* __restrict__ cur_counts,
             float* __restrict__ out)
{
    int g = blockIdx.y;
    int j = blockIdx.x * 256 + threadIdx.x;
    if (j > NNODES) return;
    float v;
    if (cur_counts[g] == 0) {
        v = (j == NNODES) ? 1.f : 0.f;
    } else {
        float m = fdec(gmaxkey[g]);
        float Z = gsum[g];
        if (j == NNODES) v = __expf(stop_scores[g] - m) / Z;
        else v = masks[(size_t)g * NNODES + j] ? __expf(scores[j] - m) / Z : 0.f;
    }
    out[(size_t)g * (NNODES + 1) + j] = v;
}

extern "C" void kernel_launch(void* const* d_in, const int* in_sizes, int n_in,
                              void* d_out, int out_size, void* d_ws, size_t ws_size,
                              hipStream_t stream) {
    const float* x        = (const float*)d_in[0];
    const int* ei         = (const int*)d_in[1];
    const int* cur_nodes  = (const int*)d_in[2];
    const int* cur_counts = (const int*)d_in[3];
    const int* masks      = (const int*)d_in[4];
    const float* W1       = (const float*)d_in[5];
    const float* att_s1   = (const float*)d_in[6];
    const float* att_d1   = (const float*)d_in[7];
    const float* b1       = (const float*)d_in[8];
    const float* W2       = (const float*)d_in[9];
    const float* att_s2   = (const float*)d_in[10];
    const float* att_d2   = (const float*)d_in[11];
    const float* b2       = (const float*)d_in[12];
    const float* action_w = (const float*)d_in[13];
    const float* action_b = (const float*)d_in[14];
    const float* stop_w   = (const float*)d_in[15];
    const float* stop_b   = (const float*)d_in[16];
    float* out = (float*)d_out;

    const int* srcp = ei;
    const int* dstp = ei + NEDGES;

    // ---- workspace layout ----
    // zero region (memset each call): deg | gmaxkey | gsum
    int* deg = (int*)d_ws;                                   // N
    unsigned* gmaxkey = (unsigned*)(deg + NNODES);           // G
    float* gsum = (float*)(gmaxkey + GG);                    // G
    char* zend = (char*)(gsum + GG);
    size_t zbytes = zend - (char*)d_ws;
    // non-zero region:
    int* rowptr = (int*)zend;                                // N+1
    int* cursor = rowptr + NNODES + 1;                       // N
    int* csr    = cursor + NNODES;                           // E
    float* h1   = (float*)(csr + NEDGES);                    // N*256
    float* h1r  = h1 + (size_t)NNODES * F1;                  // N*256
    float* as1  = h1r + (size_t)NNODES * F1;                 // N*4
    float* ad1  = as1 + (size_t)NNODES * 4;                  // N*4
    float* h2   = ad1 + (size_t)NNODES * 4;                  // N*64
    float* hf   = h2 + (size_t)NNODES * HIDN;                // N*64
    float* as2  = hf + (size_t)NNODES * HIDN;                // N
    float* ad2  = as2 + NNODES;                              // N
    float* scores = ad2 + NNODES;                            // N
    float* stop_scores = scores + NNODES;                    // G
    size_t total = (char*)(stop_scores + GG) - (char*)d_ws;
    if (total > ws_size) return;  // insufficient workspace -> clean failure

    auto cdiv = [](long long a, long long b) { return (int)((a + b - 1) / b); };

    hipMemsetAsync(d_ws, 0, zbytes, stream);

    // CSR build (dst-bucketed, src ids)
    hist_k<<<cdiv(NEDGES, 256), 256, 0, stream>>>(dstp, deg);
    scan_k<<<1, 1024, 0, stream>>>(deg, rowptr, cursor);
    scatter_k<<<cdiv(NEDGES, 256), 256, 0, stream>>>(srcp, dstp, cursor, csr);

    // layer 1
    gemm_tiled<<<dim3(cdiv(NNODES, 64), F1 / 64), 256, 0, stream>>>(x, W1, h1, NNODES, FIN, F1);
    attdots1<<<cdiv((long long)NNODES * NHEADS, 256), 256, 0, stream>>>(h1, att_s1, att_d1, as1, ad1);
    gagg1<<<cdiv(NNODES, 4), 256, 0, stream>>>(rowptr, csr, as1, ad1, h1, b1, h1r);

    // layer 2
    gemm_tiled<<<dim3(cdiv(NNODES, 64), HIDN / 64), 256, 0, stream>>>(h1r, W2, h2, NNODES, F1, HIDN);
    attdots2<<<cdiv(NNODES, 256), 256, 0, stream>>>(h2, att_s2, att_d2, as2, ad2);
    gagg2<<<cdiv(NNODES, 4), 256, 0, stream>>>(rowptr, csr, as2, ad2, h2, b2, hf);

    // heads
    scores_k<<<cdiv(NNODES, 256), 256, 0, stream>>>(hf, action_w, action_b, scores);
    ctx_k<<<GG, 64, 0, stream>>>(hf, cur_nodes, cur_counts, stop_w, stop_b, stop_scores, gmaxkey);
    redmax_k<<<dim3(64, GG), 256, 0, stream>>>(scores, masks, gmaxkey);
    redsum_k<<<dim3(64, GG), 256, 0, stream>>>(scores, masks, gmaxkey, stop_scores, gsum);
    write_k<<<dim3(cdiv(NNODES + 1, 256), GG), 256, 0, stream>>>(scores, masks, gmaxkey, gsum,
                                                                 stop_scores, cur_counts, out);
}

// Round 3
// 543.362 us; speedup vs baseline: 7.3332x; 1.2572x over previous
//
#include <hip/hip_runtime.h>
#include <hip/hip_runtime_api.h>

#define NNODES 50000
#define NEDGES 800000
#define GG 32
#define KCUR 16
#define FIN 128
#define HIDN 64
#define NHEADS 4
#define F1 256          // NHEADS*HIDN

typedef unsigned short u16;
typedef short bf8 __attribute__((ext_vector_type(8)));    // 8 bf16 in 4 VGPRs
typedef float f32x4 __attribute__((ext_vector_type(4)));

// ---- bf16 helpers ----
__device__ __forceinline__ u16 f2bf(float f) {
    unsigned u = __float_as_uint(f);
    return (u16)((u + 0x7fffu + ((u >> 16) & 1u)) >> 16);   // RNE
}
__device__ __forceinline__ float bf2f(u16 h) {
    return __uint_as_float(((unsigned)h) << 16);
}
// ---- monotone float<->uint key for atomicMax on floats ----
__device__ __forceinline__ unsigned fkey(float f) {
    unsigned u = __float_as_uint(f);
    return (u & 0x80000000u) ? ~u : (u | 0x80000000u);
}
__device__ __forceinline__ float fdec(unsigned k) {
    unsigned u = (k & 0x80000000u) ? (k & 0x7fffffffu) : ~k;
    return __uint_as_float(u);
}
__device__ __forceinline__ float lrelu(float x) { return x > 0.f ? x : 0.2f * x; }

// ---------------- cast fp32 -> bf16 (x matrix) ----------------
__global__ __launch_bounds__(256)
void cast_k(const float* __restrict__ in, u16* __restrict__ outp, int n4)
{
    int i = blockIdx.x * 256 + threadIdx.x;
    if (i >= n4) return;
    float4 v = ((const float4*)in)[i];
    ushort4 o;
    o.x = f2bf(v.x); o.y = f2bf(v.y); o.z = f2bf(v.z); o.w = f2bf(v.w);
    ((ushort4*)outp)[i] = o;
}

// ---------------- pack B[K][N] fp32 -> bf16 MFMA fragment order ----------------
// Bp[((t*S + s)*64 + lane)*8 + j] = B[s*32 + (lane>>4)*8 + j][t*16 + (lane&15)]
__global__ __launch_bounds__(256)
void pack_k(const float* __restrict__ B, u16* __restrict__ Bp, int K, int N)
{
    int idx = blockIdx.x * 256 + threadIdx.x;
    int S = K >> 5;
    int total = (N >> 4) * S * 64 * 8;
    if (idx >= total) return;
    int j = idx & 7, l = (idx >> 3) & 63, rest = idx >> 9;
    int s = rest % S, t = rest / S;
    int k = s * 32 + (l >> 4) * 8 + j;
    int n = t * 16 + (l & 15);
    Bp[idx] = f2bf(B[(size_t)k * N + n]);
}

// ---------------- MFMA bf16 GEMM: C[M,N] = A[M,K] @ B[K,N], all bf16, fp32 acc ---
// block = 256 threads = 4 waves; block covers 64 rows x N cols; wave w covers
// col tiles t = w*NT + tt (NT = N/64). M must be a multiple of 16.
template<int NT>
__global__ __launch_bounds__(256)
void gemm_mfma(const u16* __restrict__ A, const u16* __restrict__ Bp,
               u16* __restrict__ C, int M, int K, int N)
{
    int lane = threadIdx.x & 63, w = threadIdx.x >> 6;
    int m0 = blockIdx.x * 64;
    int S = K >> 5;
    int row_in = lane & 15, kq = lane >> 4;
    f32x4 acc[4][NT];
#pragma unroll
    for (int r = 0; r < 4; r++)
#pragma unroll
        for (int tt = 0; tt < NT; tt++) acc[r][tt] = (f32x4){0.f, 0.f, 0.f, 0.f};
    int R = (M - m0) >> 4; if (R > 4) R = 4;

    for (int s = 0; s < S; s++) {
        bf8 bfrag[NT];
#pragma unroll
        for (int tt = 0; tt < NT; tt++) {
            int t = w * NT + tt;
            bfrag[tt] = *(const bf8*)(Bp + (((size_t)t * S + s) * 64 + lane) * 8);
        }
        int kb = s * 32 + kq * 8;
        bf8 af[4];
#pragma unroll
        for (int r = 0; r < 4; r++)
            if (r < R) af[r] = *(const bf8*)(A + (size_t)(m0 + r * 16 + row_in) * K + kb);
#pragma unroll
        for (int r = 0; r < 4; r++)
            if (r < R)
#pragma unroll
                for (int tt = 0; tt < NT; tt++)
                    acc[r][tt] = __builtin_amdgcn_mfma_f32_16x16x32_bf16(af[r], bfrag[tt], acc[r][tt], 0, 0, 0);
    }
#pragma unroll
    for (int r = 0; r < 4; r++) {
        if (r >= R) break;
#pragma unroll
        for (int tt = 0; tt < NT; tt++) {
            int col = (w * NT + tt) * 16 + row_in;
#pragma unroll
            for (int v = 0; v < 4; v++) {
                int row = m0 + r * 16 + kq * 4 + v;
                C[(size_t)row * N + col] = f2bf(acc[r][tt][v]);
            }
        }
    }
}

// ---------------- CSR build ----------------
__global__ __launch_bounds__(256)
void hist_k(const int* __restrict__ dst, int* __restrict__ deg)
{
    int e = blockIdx.x * 256 + threadIdx.x;
    if (e >= NEDGES) return;
    atomicAdd(&deg[dst[e]], 1);
}

// single block, 1024 threads, each scans a contiguous chunk of 49 elements
__global__ __launch_bounds__(1024)
void scan_k(const int* __restrict__ deg, int* __restrict__ rowptr, int* __restrict__ cursor)
{
    const int CH = 49;   // 1024*49 = 50176 >= NNODES
    __shared__ int wpart[16];
    int tid = threadIdx.x, lane = tid & 63, wid = tid >> 6;
    int base = tid * CH;
    int s = 0;
#pragma unroll 7
    for (int i = 0; i < CH; i++) {
        int idx = base + i;
        if (idx < NNODES) s += deg[idx];
    }
    int x = s;
#pragma unroll
    for (int o = 1; o < 64; o <<= 1) {
        int y = __shfl_up(x, o);
        if (lane >= o) x += y;
    }
    if (lane == 63) wpart[wid] = x;
    __syncthreads();
    if (wid == 0 && lane < 16) {
        int v = wpart[lane], xx = v;
#pragma unroll
        for (int o = 1; o < 16; o <<= 1) {
            int y = __shfl_up(xx, o);
            if (lane >= o) xx += y;
        }
        wpart[lane] = xx - v;   // exclusive
    }
    __syncthreads();
    int run = wpart[wid] + (x - s);
#pragma unroll 7
    for (int i = 0; i < CH; i++) {
        int idx = base + i;
        if (idx < NNODES) {
            rowptr[idx] = run; cursor[idx] = run;
            run += deg[idx];
        }
    }
    if (tid == 1023) rowptr[NNODES] = run;
}

__global__ __launch_bounds__(256)
void scatter_k(const int* __restrict__ src, const int* __restrict__ dst,
               int* __restrict__ cursor, int* __restrict__ csr)
{
    int e = blockIdx.x * 256 + threadIdx.x;
    if (e >= NEDGES) return;
    int d = dst[e];
    int pos = atomicAdd(&cursor[d], 1);
    csr[pos] = src[e];
}

// ---------------- layer-1 attention dots from bf16 h1 ----------------
__global__ __launch_bounds__(256)
void attdots1(const u16* __restrict__ h1b, const float* __restrict__ asw,
              const float* __restrict__ adw, float* __restrict__ as1, float* __restrict__ ad1)
{
    int gid = blockIdx.x * 256 + threadIdx.x;
    if (gid >= NNODES * NHEADS) return;
    int n = gid >> 2, h = gid & 3;
    const bf8* hv = (const bf8*)(h1b + (size_t)n * F1 + h * HIDN);
    const float* sw = asw + h * HIDN;
    const float* dw = adw + h * HIDN;
    float s = 0.f, d = 0.f;
#pragma unroll
    for (int i = 0; i < 8; i++) {
        bf8 hb = hv[i];
#pragma unroll
        for (int j = 0; j < 8; j++) {
            float hf_ = bf2f((u16)hb[j]);
            s = fmaf(hf_, sw[i * 8 + j], s);
            d = fmaf(hf_, dw[i * 8 + j], d);
        }
    }
    as1[gid] = s; ad1[gid] = d;
}

// ---------------- layer-1 gather aggregation ----------------
// one wave per dst. Lanes 0-31 and 32-63 process alternate edges; each lane
// covers 8 bf16 channels (c0 = (lane&31)*8). Virtual edge p=0 is the self loop.
// Output written bf16 (feeds GEMM2).
__global__ __launch_bounds__(256)
void gagg1(const int* __restrict__ rowptr, const int* __restrict__ csr,
           const float* __restrict__ as1, const float* __restrict__ ad1,
           const u16* __restrict__ h1b, const float* __restrict__ b1,
           u16* __restrict__ outp)
{
    int wid = threadIdx.x >> 6, lane = threadIdx.x & 63;
    int d = blockIdx.x * 4 + wid;
    if (d >= NNODES) return;
    int beg = rowptr[d];
    int tot = rowptr[d + 1] - beg + 1;     // + self loop
    int half = lane >> 5;
    int l31 = lane & 31;
    int h = l31 >> 3;
    int c0 = l31 << 3;
    float adh = ad1[d * 4 + h];
    float den = 0.f;
    float acc[8];
#pragma unroll
    for (int j = 0; j < 8; j++) acc[j] = 0.f;

    for (int p = half; p < tot; p += 2) {
        int s = (p == 0) ? d : csr[beg + p - 1];
        float ex = __expf(lrelu(as1[s * 4 + h] + adh));
        den += ex;
        bf8 hv = *(const bf8*)(h1b + (size_t)s * F1 + c0);
#pragma unroll
        for (int j = 0; j < 8; j++) acc[j] = fmaf(ex, bf2f((u16)hv[j]), acc[j]);
    }
    // combine halves
    den += __shfl_xor(den, 32);
#pragma unroll
    for (int j = 0; j < 8; j++) acc[j] += __shfl_xor(acc[j], 32);

    if (lane < 32) {
        float rden = 1.f / den;
        float4 blo = *(const float4*)(b1 + c0);
        float4 bhi = *(const float4*)(b1 + c0 + 4);
        float bb[8] = {blo.x, blo.y, blo.z, blo.w, bhi.x, bhi.y, bhi.z, bhi.w};
        bf8 o;
#pragma unroll
        for (int j = 0; j < 8; j++)
            o[j] = (short)f2bf(fmaxf(fmaf(acc[j], rden, bb[j]), 0.f));
        *(bf8*)(outp + (size_t)d * F1 + c0) = o;
    }
}

// ---------------- layer-2 attention dots from bf16 h2 ----------------
__global__ __launch_bounds__(256)
void attdots2(const u16* __restrict__ h2b, const float* __restrict__ asw,
              const float* __restrict__ adw, float* __restrict__ as2, float* __restrict__ ad2)
{
    int n = blockIdx.x * 256 + threadIdx.x;
    if (n >= NNODES) return;
    const bf8* hv = (const bf8*)(h2b + (size_t)n * HIDN);
    float s = 0.f, d = 0.f;
#pragma unroll
    for (int i = 0; i < 8; i++) {
        bf8 hb = hv[i];
#pragma unroll
        for (int j = 0; j < 8; j++) {
            float hf_ = bf2f((u16)hb[j]);
            s = fmaf(hf_, asw[i * 8 + j], s);
            d = fmaf(hf_, adw[i * 8 + j], d);
        }
    }
    as2[n] = s; ad2[n] = d;
}

// ---------------- layer-2 gather aggregation ----------------
// one wave per dst; 4 quarters process 4 edges/iter; lane covers 4 channels
// (c0 = (lane&15)*4). Virtual edge p=0 = self loop. Output fp32 hf.
__global__ __launch_bounds__(256)
void gagg2(const int* __restrict__ rowptr, const int* __restrict__ csr,
           const float* __restrict__ as2, const float* __restrict__ ad2,
           const u16* __restrict__ h2b, const float* __restrict__ b2,
           float* __restrict__ outp)
{
    int wid = threadIdx.x >> 6, lane = threadIdx.x & 63;
    int d = blockIdx.x * 4 + wid;
    if (d >= NNODES) return;
    int beg = rowptr[d];
    int tot = rowptr[d + 1] - beg + 1;
    int q = lane >> 4;
    int c0 = (lane & 15) << 2;
    float ads = ad2[d];
    float den = 0.f;
    float a0 = 0.f, a1 = 0.f, a2 = 0.f, a3 = 0.f;

    for (int p = q; p < tot; p += 4) {
        int s = (p == 0) ? d : csr[beg + p - 1];
        float ex = __expf(lrelu(as2[s] + ads));
        den += ex;
        ushort4 hv = *(const ushort4*)(h2b + (size_t)s * HIDN + c0);
        a0 = fmaf(ex, bf2f(hv.x), a0);
        a1 = fmaf(ex, bf2f(hv.y), a1);
        a2 = fmaf(ex, bf2f(hv.z), a2);
        a3 = fmaf(ex, bf2f(hv.w), a3);
    }
    den += __shfl_xor(den, 16);  a0 += __shfl_xor(a0, 16);
    a1 += __shfl_xor(a1, 16);    a2 += __shfl_xor(a2, 16);
    a3 += __shfl_xor(a3, 16);
    den += __shfl_xor(den, 32);  a0 += __shfl_xor(a0, 32);
    a1 += __shfl_xor(a1, 32);    a2 += __shfl_xor(a2, 32);
    a3 += __shfl_xor(a3, 32);

    if (lane < 16) {
        float rden = 1.f / den;
        float4 bb = *(const float4*)(b2 + c0);
        float4 o;
        o.x = fmaf(a0, rden, bb.x);
        o.y = fmaf(a1, rden, bb.y);
        o.z = fmaf(a2, rden, bb.z);
        o.w = fmaf(a3, rden, bb.w);
        *(float4*)(outp + (size_t)d * HIDN + c0) = o;
    }
}

// ---------------- node scores = tanh(hf @ action_w + action_b) ----------------
__global__ __launch_bounds__(256)
void scores_k(const float* __restrict__ hf, const float* __restrict__ aw,
              const float* __restrict__ ab, float* __restrict__ scores)
{
    int n = blockIdx.x * 256 + threadIdx.x;
    if (n >= NNODES) return;
    const float4* hv = (const float4*)(hf + (size_t)n * HIDN);
    const float4* wv = (const float4*)aw;
    float s = 0.f;
#pragma unroll 4
    for (int i = 0; i < 16; i++) {
        float4 hh = hv[i], ww = wv[i];
        s += hh.x * ww.x + hh.y * ww.y + hh.z * ww.z + hh.w * ww.w;
    }
    scores[n] = tanhf(s + ab[0]);
}

// ---------------- per-graph context pooling + stop score ----------------
__global__ __launch_bounds__(64)
void ctx_k(const float* __restrict__ hf, const int* __restrict__ cur_nodes,
           const int* __restrict__ cur_counts, const float* __restrict__ sw,
           const float* __restrict__ sb, float* __restrict__ stop_scores,
           unsigned* __restrict__ gmaxkey)
{
    int g = blockIdx.x;
    int c = threadIdx.x;
    int cnt = cur_counts[g];
    float s = 0.f;
    for (int k = 0; k < KCUR; k++) {
        if (k < cnt) {
            int node = cur_nodes[g * KCUR + k];
            s += hf[(size_t)node * HIDN + c];
        }
    }
    float ctx = s / (float)(cnt > 1 ? cnt : 1);
    float p = ctx * sw[c];
    for (int o = 32; o; o >>= 1) p += __shfl_down(p, o);
    if (c == 0) {
        float st = tanhf(p + sb[0]);
        stop_scores[g] = st;
        atomicMax(&gmaxkey[g], fkey(st));
    }
}

// ---------------- per-graph masked max over node scores ----------------
__global__ __launch_bounds__(256)
void redmax_k(const float* __restrict__ scores, const int* __restrict__ masks,
              unsigned* __restrict__ gmaxkey)
{
    __shared__ float lds[4];
    int g = blockIdx.y;
    float lm = -3.0e38f;
    for (int n = blockIdx.x * 256 + threadIdx.x; n < NNODES; n += gridDim.x * 256)
        if (masks[(size_t)g * NNODES + n]) lm = fmaxf(lm, scores[n]);
    for (int o = 32; o; o >>= 1) lm = fmaxf(lm, __shfl_down(lm, o));
    if ((threadIdx.x & 63) == 0) lds[threadIdx.x >> 6] = lm;
    __syncthreads();
    if (threadIdx.x == 0) {
        lm = fmaxf(fmaxf(lds[0], lds[1]), fmaxf(lds[2], lds[3]));
        atomicMax(&gmaxkey[g], fkey(lm));
    }
}

// ---------------- per-graph masked exp-sum ----------------
__global__ __launch_bounds__(256)
void redsum_k(const float* __restrict__ scores, const int* __restrict__ masks,
              const unsigned* __restrict__ gmaxkey, const float* __restrict__ stop_scores,
              float* __restrict__ gsum)
{
    __shared__ float lds[4];
    int g = blockIdx.y;
    float m = fdec(gmaxkey[g]);
    float ls = 0.f;
    for (int n = blockIdx.x * 256 + threadIdx.x; n < NNODES; n += gridDim.x * 256)
        if (masks[(size_t)g * NNODES + n]) ls += __expf(scores[n] - m);
    for (int o = 32; o; o >>= 1) ls += __shfl_down(ls, o);
    if ((threadIdx.x & 63) == 0) lds[threadIdx.x >> 6] = ls;
    __syncthreads();
    if (threadIdx.x == 0) {
        ls = lds[0] + lds[1] + lds[2] + lds[3];
        if (blockIdx.x == 0) ls += __expf(stop_scores[g] - m);
        atomicAdd(&gsum[g], ls);
    }
}

// ---------------- final probability write ----------------
__global__ __launch_bounds__(256)
void write_k(const float* __restrict__ scores, const int* __restrict__ masks,
             const unsigned* __restrict__ gmaxkey, const float* __restrict__ gsum,
             const float* __restrict__ stop_scores, const int* __restrict__ cur_counts,
             float* __restrict__ out)
{
    int g = blockIdx.y;
    int j = blockIdx.x * 256 + threadIdx.x;
    if (j > NNODES) return;
    float v;
    if (cur_counts[g] == 0) {
        v = (j == NNODES) ? 1.f : 0.f;
    } else {
        float m = fdec(gmaxkey[g]);
        float Z = gsum[g];
        if (j == NNODES) v = __expf(stop_scores[g] - m) / Z;
        else v = masks[(size_t)g * NNODES + j] ? __expf(scores[j] - m) / Z : 0.f;
    }
    out[(size_t)g * (NNODES + 1) + j] = v;
}

extern "C" void kernel_launch(void* const* d_in, const int* in_sizes, int n_in,
                              void* d_out, int out_size, void* d_ws, size_t ws_size,
                              hipStream_t stream) {
    const float* x        = (const float*)d_in[0];
    const int* ei         = (const int*)d_in[1];
    const int* cur_nodes  = (const int*)d_in[2];
    const int* cur_counts = (const int*)d_in[3];
    const int* masks      = (const int*)d_in[4];
    const float* W1       = (const float*)d_in[5];
    const float* att_s1   = (const float*)d_in[6];
    const float* att_d1   = (const float*)d_in[7];
    const float* b1       = (const float*)d_in[8];
    const float* W2       = (const float*)d_in[9];
    const float* att_s2   = (const float*)d_in[10];
    const float* att_d2   = (const float*)d_in[11];
    const float* b2       = (const float*)d_in[12];
    const float* action_w = (const float*)d_in[13];
    const float* action_b = (const float*)d_in[14];
    const float* stop_w   = (const float*)d_in[15];
    const float* stop_b   = (const float*)d_in[16];
    float* out = (float*)d_out;

    const int* srcp = ei;
    const int* dstp = ei + NEDGES;

    // ---- workspace layout (16B-aligned segments) ----
    // zero region: deg | gmaxkey | gsum
    int* deg = (int*)d_ws;                                   // 50000
    unsigned* gmaxkey = (unsigned*)(deg + NNODES);           // 32
    float* gsum = (float*)(gmaxkey + GG);                    // 32
    char* zend = (char*)(gsum + GG);
    size_t zbytes = zend - (char*)d_ws;
    // non-zero region:
    int* rowptr = (int*)zend;                                // 50004 (padded)
    int* cursor = rowptr + NNODES + 4;                       // 50000
    int* csr    = cursor + NNODES;                           // 800000
    u16* xb     = (u16*)(csr + NEDGES);                      // N*128
    u16* W1p    = xb + (size_t)NNODES * FIN;                 // 32768
    u16* W2p    = W1p + 32768;                               // 16384
    u16* h1b    = W2p + 16384;                               // N*256
    u16* h1rb   = h1b + (size_t)NNODES * F1;                 // N*256
    u16* h2b    = h1rb + (size_t)NNODES * F1;                // N*64
    float* as1  = (float*)(h2b + (size_t)NNODES * HIDN);     // N*4
    float* ad1  = as1 + (size_t)NNODES * 4;                  // N*4
    float* as2  = ad1 + (size_t)NNODES * 4;                  // N
    float* ad2  = as2 + NNODES;                              // N
    float* hf   = ad2 + NNODES;                              // N*64
    float* scores = hf + (size_t)NNODES * HIDN;              // N
    float* stop_scores = scores + NNODES;                    // G
    size_t total = (char*)(stop_scores + GG) - (char*)d_ws;
    if (total > ws_size) return;

    auto cdiv = [](long long a, long long b) { return (int)((a + b - 1) / b); };

    hipMemsetAsync(d_ws, 0, zbytes, stream);

    // CSR build (dst-bucketed src ids)
    hist_k<<<cdiv(NEDGES, 256), 256, 0, stream>>>(dstp, deg);
    scan_k<<<1, 1024, 0, stream>>>(deg, rowptr, cursor);
    scatter_k<<<cdiv(NEDGES, 256), 256, 0, stream>>>(srcp, dstp, cursor, csr);

    // casts + weight packs
    cast_k<<<cdiv((long long)NNODES * FIN / 4, 256), 256, 0, stream>>>(x, xb, NNODES * FIN / 4);
    pack_k<<<cdiv(32768, 256), 256, 0, stream>>>(W1, W1p, FIN, F1);
    pack_k<<<cdiv(16384, 256), 256, 0, stream>>>(W2, W2p, F1, HIDN);

    // layer 1
    gemm_mfma<4><<<dim3(cdiv(NNODES, 64), 1), 256, 0, stream>>>(xb, W1p, h1b, NNODES, FIN, F1);
    attdots1<<<cdiv((long long)NNODES * NHEADS, 256), 256, 0, stream>>>(h1b, att_s1, att_d1, as1, ad1);
    gagg1<<<cdiv(NNODES, 4), 256, 0, stream>>>(rowptr, csr, as1, ad1, h1b, b1, h1rb);

    // layer 2
    gemm_mfma<1><<<dim3(cdiv(NNODES, 64), 1), 256, 0, stream>>>(h1rb, W2p, h2b, NNODES, F1, HIDN);
    attdots2<<<cdiv(NNODES, 256), 256, 0, stream>>>(h2b, att_s2, att_d2, as2, ad2);
    gagg2<<<cdiv(NNODES, 4), 256, 0, stream>>>(rowptr, csr, as2, ad2, h2b, b2, hf);

    // heads
    scores_k<<<cdiv(NNODES, 256), 256, 0, stream>>>(hf, action_w, action_b, scores);
    ctx_k<<<GG, 64, 0, stream>>>(hf, cur_nodes, cur_counts, stop_w, stop_b, stop_scores, gmaxkey);
    redmax_k<<<dim3(64, GG), 256, 0, stream>>>(scores, masks, gmaxkey);
    redsum_k<<<dim3(64, GG), 256, 0, stream>>>(scores, masks, gmaxkey, stop_scores, gsum);
    write_k<<<dim3(cdiv(NNODES + 1, 256), GG), 256, 0, stream>>>(scores, masks, gmaxkey, gsum,
                                                                 stop_scores, cur_counts, out);
}

// Round 4
// 436.283 us; speedup vs baseline: 9.1330x; 1.2454x over previous
//
#include <hip/hip_runtime.h>
#include <hip/hip_runtime_api.h>

#define NNODES 50000
#define NEDGES 800000
#define GG 32
#define KCUR 16
#define FIN 128
#define HIDN 64
#define NHEADS 4
#define F1 256          // NHEADS*HIDN
#define NCHUNK 196      // ceil(NNODES/256)

typedef unsigned short u16;
typedef short bf8 __attribute__((ext_vector_type(8)));    // 8 bf16 in 4 VGPRs
typedef float f32x4 __attribute__((ext_vector_type(4)));

// ---- bf16 helpers ----
__device__ __forceinline__ u16 f2bf(float f) {
    unsigned u = __float_as_uint(f);
    return (u16)((u + 0x7fffu + ((u >> 16) & 1u)) >> 16);   // RNE
}
__device__ __forceinline__ float bf2f(u16 h) {
    return __uint_as_float(((unsigned)h) << 16);
}
// ---- monotone float<->uint key for atomicMax on floats ----
__device__ __forceinline__ unsigned fkey(float f) {
    unsigned u = __float_as_uint(f);
    return (u & 0x80000000u) ? ~u : (u | 0x80000000u);
}
__device__ __forceinline__ float fdec(unsigned k) {
    unsigned u = (k & 0x80000000u) ? (k & 0x7fffffffu) : ~k;
    return __uint_as_float(u);
}
__device__ __forceinline__ float lrelu(float x) { return x > 0.f ? x : 0.2f * x; }

// ---------------- cast fp32 -> bf16 (x matrix) ----------------
__global__ __launch_bounds__(256)
void cast_k(const float* __restrict__ in, u16* __restrict__ outp, int n4)
{
    int i = blockIdx.x * 256 + threadIdx.x;
    if (i >= n4) return;
    float4 v = ((const float4*)in)[i];
    ushort4 o;
    o.x = f2bf(v.x); o.y = f2bf(v.y); o.z = f2bf(v.z); o.w = f2bf(v.w);
    ((ushort4*)outp)[i] = o;
}

// ---------------- pack B[K][N] fp32 -> bf16 MFMA fragment order ----------------
// Bp[((t*S + s)*64 + lane)*8 + j] = B[s*32 + (lane>>4)*8 + j][t*16 + (lane&15)]
__global__ __launch_bounds__(256)
void pack_k(const float* __restrict__ B, u16* __restrict__ Bp, int K, int N)
{
    int idx = blockIdx.x * 256 + threadIdx.x;
    int S = K >> 5;
    int total = (N >> 4) * S * 64 * 8;
    if (idx >= total) return;
    int j = idx & 7, l = (idx >> 3) & 63, rest = idx >> 9;
    int s = rest % S, t = rest / S;
    int k = s * 32 + (l >> 4) * 8 + j;
    int n = t * 16 + (l & 15);
    Bp[idx] = f2bf(B[(size_t)k * N + n]);
}

// ---------------- MFMA bf16 GEMM: C[M,N] = A[M,K] @ B[K,N], all bf16, fp32 acc ---
template<int NT>
__global__ __launch_bounds__(256)
void gemm_mfma(const u16* __restrict__ A, const u16* __restrict__ Bp,
               u16* __restrict__ C, int M, int K, int N)
{
    int lane = threadIdx.x & 63, w = threadIdx.x >> 6;
    int m0 = blockIdx.x * 64;
    int S = K >> 5;
    int row_in = lane & 15, kq = lane >> 4;
    f32x4 acc[4][NT];
#pragma unroll
    for (int r = 0; r < 4; r++)
#pragma unroll
        for (int tt = 0; tt < NT; tt++) acc[r][tt] = (f32x4){0.f, 0.f, 0.f, 0.f};
    int R = (M - m0) >> 4; if (R > 4) R = 4;

    for (int s = 0; s < S; s++) {
        bf8 bfrag[NT];
#pragma unroll
        for (int tt = 0; tt < NT; tt++) {
            int t = w * NT + tt;
            bfrag[tt] = *(const bf8*)(Bp + (((size_t)t * S + s) * 64 + lane) * 8);
        }
        int kb = s * 32 + kq * 8;
        bf8 af[4];
#pragma unroll
        for (int r = 0; r < 4; r++)
            if (r < R) af[r] = *(const bf8*)(A + (size_t)(m0 + r * 16 + row_in) * K + kb);
#pragma unroll
        for (int r = 0; r < 4; r++)
            if (r < R)
#pragma unroll
                for (int tt = 0; tt < NT; tt++)
                    acc[r][tt] = __builtin_amdgcn_mfma_f32_16x16x32_bf16(af[r], bfrag[tt], acc[r][tt], 0, 0, 0);
    }
#pragma unroll
    for (int r = 0; r < 4; r++) {
        if (r >= R) break;
#pragma unroll
        for (int tt = 0; tt < NT; tt++) {
            int col = (w * NT + tt) * 16 + row_in;
#pragma unroll
            for (int v = 0; v < 4; v++) {
                int row = m0 + r * 16 + kq * 4 + v;
                C[(size_t)row * N + col] = f2bf(acc[r][tt][v]);
            }
        }
    }
}

// ---------------- CSR build ----------------
__global__ __launch_bounds__(256)
void hist_k(const int* __restrict__ dst, int* __restrict__ deg)
{
    int e = blockIdx.x * 256 + threadIdx.x;
    if (e >= NEDGES) return;
    atomicAdd(&deg[dst[e]], 1);
}

// phase 1: per-256-chunk sums
__global__ __launch_bounds__(256)
void chunksum_k(const int* __restrict__ deg, int* __restrict__ csum)
{
    __shared__ int ws[4];
    int i = blockIdx.x * 256 + threadIdx.x;
    int v = (i < NNODES) ? deg[i] : 0;
#pragma unroll
    for (int o = 32; o; o >>= 1) v += __shfl_down(v, o);
    if ((threadIdx.x & 63) == 0) ws[threadIdx.x >> 6] = v;
    __syncthreads();
    if (threadIdx.x == 0) csum[blockIdx.x] = ws[0] + ws[1] + ws[2] + ws[3];
}

// phase 2: exclusive scan of NCHUNK chunk sums (one block)
__global__ __launch_bounds__(256)
void chunkscan_k(int* __restrict__ csum)
{
    __shared__ int ws[4];
    int tid = threadIdx.x, lane = tid & 63, wid = tid >> 6;
    int v = (tid < NCHUNK) ? csum[tid] : 0;
    int x = v;
#pragma unroll
    for (int o = 1; o < 64; o <<= 1) {
        int y = __shfl_up(x, o);
        if (lane >= o) x += y;
    }
    if (lane == 63) ws[wid] = x;
    __syncthreads();
    int off = 0;
    for (int w = 0; w < wid; w++) off += ws[w];
    if (tid < NCHUNK) csum[tid] = off + x - v;   // exclusive
}

// phase 3: expand to rowptr/cursor with block-level exclusive scan
__global__ __launch_bounds__(256)
void expand_k(const int* __restrict__ deg, const int* __restrict__ csum,
              int* __restrict__ rowptr, int* __restrict__ cursor)
{
    __shared__ int ws[4];
    int i = blockIdx.x * 256 + threadIdx.x;
    int lane = threadIdx.x & 63, wid = threadIdx.x >> 6;
    int v = (i < NNODES) ? deg[i] : 0;
    int x = v;
#pragma unroll
    for (int o = 1; o < 64; o <<= 1) {
        int y = __shfl_up(x, o);
        if (lane >= o) x += y;
    }
    if (lane == 63) ws[wid] = x;
    __syncthreads();
    int off = csum[blockIdx.x];
    for (int w = 0; w < wid; w++) off += ws[w];
    int excl = off + x - v;
    if (i < NNODES) { rowptr[i] = excl; cursor[i] = excl; }
    if (i == 0) rowptr[NNODES] = NEDGES;
}

__global__ __launch_bounds__(256)
void scatter_k(const int* __restrict__ src, const int* __restrict__ dst,
               int* __restrict__ cursor, int* __restrict__ csr)
{
    int e = blockIdx.x * 256 + threadIdx.x;
    if (e >= NEDGES) return;
    int d = dst[e];
    int pos = atomicAdd(&cursor[d], 1);
    csr[pos] = src[e];
}

// ---------------- layer-1 attention dots from bf16 h1 ----------------
__global__ __launch_bounds__(256)
void attdots1(const u16* __restrict__ h1b, const float* __restrict__ asw,
              const float* __restrict__ adw, float* __restrict__ as1, float* __restrict__ ad1)
{
    int gid = blockIdx.x * 256 + threadIdx.x;
    if (gid >= NNODES * NHEADS) return;
    int n = gid >> 2, h = gid & 3;
    const bf8* hv = (const bf8*)(h1b + (size_t)n * F1 + h * HIDN);
    const float* sw = asw + h * HIDN;
    const float* dw = adw + h * HIDN;
    float s = 0.f, d = 0.f;
#pragma unroll
    for (int i = 0; i < 8; i++) {
        bf8 hb = hv[i];
#pragma unroll
        for (int j = 0; j < 8; j++) {
            float hf_ = bf2f((u16)hb[j]);
            s = fmaf(hf_, sw[i * 8 + j], s);
            d = fmaf(hf_, dw[i * 8 + j], d);
        }
    }
    as1[gid] = s; ad1[gid] = d;
}

// ---------------- layer-1 gather aggregation ----------------
__global__ __launch_bounds__(256)
void gagg1(const int* __restrict__ rowptr, const int* __restrict__ csr,
           const float* __restrict__ as1, const float* __restrict__ ad1,
           const u16* __restrict__ h1b, const float* __restrict__ b1,
           u16* __restrict__ outp)
{
    int wid = threadIdx.x >> 6, lane = threadIdx.x & 63;
    int d = blockIdx.x * 4 + wid;
    if (d >= NNODES) return;
    int beg = rowptr[d];
    int tot = rowptr[d + 1] - beg + 1;     // + self loop
    int half = lane >> 5;
    int l31 = lane & 31;
    int h = l31 >> 3;
    int c0 = l31 << 3;
    float adh = ad1[d * 4 + h];
    float den = 0.f;
    float acc[8];
#pragma unroll
    for (int j = 0; j < 8; j++) acc[j] = 0.f;

    for (int p = half; p < tot; p += 2) {
        int s = (p == 0) ? d : csr[beg + p - 1];
        float ex = __expf(lrelu(as1[s * 4 + h] + adh));
        den += ex;
        bf8 hv = *(const bf8*)(h1b + (size_t)s * F1 + c0);
#pragma unroll
        for (int j = 0; j < 8; j++) acc[j] = fmaf(ex, bf2f((u16)hv[j]), acc[j]);
    }
    den += __shfl_xor(den, 32);
#pragma unroll
    for (int j = 0; j < 8; j++) acc[j] += __shfl_xor(acc[j], 32);

    if (lane < 32) {
        float rden = 1.f / den;
        float4 blo = *(const float4*)(b1 + c0);
        float4 bhi = *(const float4*)(b1 + c0 + 4);
        float bb[8] = {blo.x, blo.y, blo.z, blo.w, bhi.x, bhi.y, bhi.z, bhi.w};
        bf8 o;
#pragma unroll
        for (int j = 0; j < 8; j++)
            o[j] = (short)f2bf(fmaxf(fmaf(acc[j], rden, bb[j]), 0.f));
        *(bf8*)(outp + (size_t)d * F1 + c0) = o;
    }
}

// ---------------- layer-2 attention dots from bf16 h2 ----------------
__global__ __launch_bounds__(256)
void attdots2(const u16* __restrict__ h2b, const float* __restrict__ asw,
              const float* __restrict__ adw, float* __restrict__ as2, float* __restrict__ ad2)
{
    int n = blockIdx.x * 256 + threadIdx.x;
    if (n >= NNODES) return;
    const bf8* hv = (const bf8*)(h2b + (size_t)n * HIDN);
    float s = 0.f, d = 0.f;
#pragma unroll
    for (int i = 0; i < 8; i++) {
        bf8 hb = hv[i];
#pragma unroll
        for (int j = 0; j < 8; j++) {
            float hf_ = bf2f((u16)hb[j]);
            s = fmaf(hf_, asw[i * 8 + j], s);
            d = fmaf(hf_, adw[i * 8 + j], d);
        }
    }
    as2[n] = s; ad2[n] = d;
}

// ---------------- layer-2 gather aggregation ----------------
__global__ __launch_bounds__(256)
void gagg2(const int* __restrict__ rowptr, const int* __restrict__ csr,
           const float* __restrict__ as2, const float* __restrict__ ad2,
           const u16* __restrict__ h2b, const float* __restrict__ b2,
           float* __restrict__ outp)
{
    int wid = threadIdx.x >> 6, lane = threadIdx.x & 63;
    int d = blockIdx.x * 4 + wid;
    if (d >= NNODES) return;
    int beg = rowptr[d];
    int tot = rowptr[d + 1] - beg + 1;
    int q = lane >> 4;
    int c0 = (lane & 15) << 2;
    float ads = ad2[d];
    float den = 0.f;
    float a0 = 0.f, a1 = 0.f, a2 = 0.f, a3 = 0.f;

    for (int p = q; p < tot; p += 4) {
        int s = (p == 0) ? d : csr[beg + p - 1];
        float ex = __expf(lrelu(as2[s] + ads));
        den += ex;
        ushort4 hv = *(const ushort4*)(h2b + (size_t)s * HIDN + c0);
        a0 = fmaf(ex, bf2f(hv.x), a0);
        a1 = fmaf(ex, bf2f(hv.y), a1);
        a2 = fmaf(ex, bf2f(hv.z), a2);
        a3 = fmaf(ex, bf2f(hv.w), a3);
    }
    den += __shfl_xor(den, 16);  a0 += __shfl_xor(a0, 16);
    a1 += __shfl_xor(a1, 16);    a2 += __shfl_xor(a2, 16);
    a3 += __shfl_xor(a3, 16);
    den += __shfl_xor(den, 32);  a0 += __shfl_xor(a0, 32);
    a1 += __shfl_xor(a1, 32);    a2 += __shfl_xor(a2, 32);
    a3 += __shfl_xor(a3, 32);

    if (lane < 16) {
        float rden = 1.f / den;
        float4 bb = *(const float4*)(b2 + c0);
        float4 o;
        o.x = fmaf(a0, rden, bb.x);
        o.y = fmaf(a1, rden, bb.y);
        o.z = fmaf(a2, rden, bb.z);
        o.w = fmaf(a3, rden, bb.w);
        *(float4*)(outp + (size_t)d * HIDN + c0) = o;
    }
}

// ---------------- node scores = tanh(hf @ action_w + action_b) ----------------
__global__ __launch_bounds__(256)
void scores_k(const float* __restrict__ hf, const float* __restrict__ aw,
              const float* __restrict__ ab, float* __restrict__ scores)
{
    int n = blockIdx.x * 256 + threadIdx.x;
    if (n >= NNODES) return;
    const float4* hv = (const float4*)(hf + (size_t)n * HIDN);
    const float4* wv = (const float4*)aw;
    float s = 0.f;
#pragma unroll 4
    for (int i = 0; i < 16; i++) {
        float4 hh = hv[i], ww = wv[i];
        s += hh.x * ww.x + hh.y * ww.y + hh.z * ww.z + hh.w * ww.w;
    }
    scores[n] = tanhf(s + ab[0]);
}

// ---------------- per-graph context pooling + stop score ----------------
__global__ __launch_bounds__(64)
void ctx_k(const float* __restrict__ hf, const int* __restrict__ cur_nodes,
           const int* __restrict__ cur_counts, const float* __restrict__ sw,
           const float* __restrict__ sb, float* __restrict__ stop_scores,
           unsigned* __restrict__ gmaxkey)
{
    int g = blockIdx.x;
    int c = threadIdx.x;
    int cnt = cur_counts[g];
    float s = 0.f;
    for (int k = 0; k < KCUR; k++) {
        if (k < cnt) {
            int node = cur_nodes[g * KCUR + k];
            s += hf[(size_t)node * HIDN + c];
        }
    }
    float ctx = s / (float)(cnt > 1 ? cnt : 1);
    float p = ctx * sw[c];
    for (int o = 32; o; o >>= 1) p += __shfl_down(p, o);
    if (c == 0) {
        float st = tanhf(p + sb[0]);
        stop_scores[g] = st;
        atomicMax(&gmaxkey[g], fkey(st));
    }
}

// ---------------- per-graph masked max over node scores ----------------
__global__ __launch_bounds__(256)
void redmax_k(const float* __restrict__ scores, const int* __restrict__ masks,
              unsigned* __restrict__ gmaxkey)
{
    __shared__ float lds[4];
    int g = blockIdx.y;
    float lm = -3.0e38f;
    for (int n = blockIdx.x * 256 + threadIdx.x; n < NNODES; n += gridDim.x * 256)
        if (masks[(size_t)g * NNODES + n]) lm = fmaxf(lm, scores[n]);
    for (int o = 32; o; o >>= 1) lm = fmaxf(lm, __shfl_down(lm, o));
    if ((threadIdx.x & 63) == 0) lds[threadIdx.x >> 6] = lm;
    __syncthreads();
    if (threadIdx.x == 0) {
        lm = fmaxf(fmaxf(lds[0], lds[1]), fmaxf(lds[2], lds[3]));
        atomicMax(&gmaxkey[g], fkey(lm));
    }
}

// ---------------- per-graph masked exp-sum ----------------
__global__ __launch_bounds__(256)
void redsum_k(const float* __restrict__ scores, const int* __restrict__ masks,
              const unsigned* __restrict__ gmaxkey, const float* __restrict__ stop_scores,
              float* __restrict__ gsum)
{
    __shared__ float lds[4];
    int g = blockIdx.y;
    float m = fdec(gmaxkey[g]);
    float ls = 0.f;
    for (int n = blockIdx.x * 256 + threadIdx.x; n < NNODES; n += gridDim.x * 256)
        if (masks[(size_t)g * NNODES + n]) ls += __expf(scores[n] - m);
    for (int o = 32; o; o >>= 1) ls += __shfl_down(ls, o);
    if ((threadIdx.x & 63) == 0) lds[threadIdx.x >> 6] = ls;
    __syncthreads();
    if (threadIdx.x == 0) {
        ls = lds[0] + lds[1] + lds[2] + lds[3];
        if (blockIdx.x == 0) ls += __expf(stop_scores[g] - m);
        atomicAdd(&gsum[g], ls);
    }
}

// ---------------- final probability write ----------------
__global__ __launch_bounds__(256)
void write_k(const float* __restrict__ scores, const int* __restrict__ masks,
             const unsigned* __restrict__ gmaxkey, const float* __restrict__ gsum,
             const float* __restrict__ stop_scores, const int* __restrict__ cur_counts,
             float* __restrict__ out)
{
    int g = blockIdx.y;
    int j = blockIdx.x * 256 + threadIdx.x;
    if (j > NNODES) return;
    float v;
    if (cur_counts[g] == 0) {
        v = (j == NNODES) ? 1.f : 0.f;
    } else {
        float m = fdec(gmaxkey[g]);
        float Z = gsum[g];
        if (j == NNODES) v = __expf(stop_scores[g] - m) / Z;
        else v = masks[(size_t)g * NNODES + j] ? __expf(scores[j] - m) / Z : 0.f;
    }
    out[(size_t)g * (NNODES + 1) + j] = v;
}

extern "C" void kernel_launch(void* const* d_in, const int* in_sizes, int n_in,
                              void* d_out, int out_size, void* d_ws, size_t ws_size,
                              hipStream_t stream) {
    const float* x        = (const float*)d_in[0];
    const int* ei         = (const int*)d_in[1];
    const int* cur_nodes  = (const int*)d_in[2];
    const int* cur_counts = (const int*)d_in[3];
    const int* masks      = (const int*)d_in[4];
    const float* W1       = (const float*)d_in[5];
    const float* att_s1   = (const float*)d_in[6];
    const float* att_d1   = (const float*)d_in[7];
    const float* b1       = (const float*)d_in[8];
    const float* W2       = (const float*)d_in[9];
    const float* att_s2   = (const float*)d_in[10];
    const float* att_d2   = (const float*)d_in[11];
    const float* b2       = (const float*)d_in[12];
    const float* action_w = (const float*)d_in[13];
    const float* action_b = (const float*)d_in[14];
    const float* stop_w   = (const float*)d_in[15];
    const float* stop_b   = (const float*)d_in[16];
    float* out = (float*)d_out;

    const int* srcp = ei;
    const int* dstp = ei + NEDGES;

    // ---- workspace layout ----
    // zero region: deg | gmaxkey | gsum
    int* deg = (int*)d_ws;                                   // 50000
    unsigned* gmaxkey = (unsigned*)(deg + NNODES);           // 32
    float* gsum = (float*)(gmaxkey + GG);                    // 32
    char* zend = (char*)(gsum + GG);
    size_t zbytes = zend - (char*)d_ws;
    // non-zero region:
    int* csum   = (int*)zend;                                // NCHUNK (+pad)
    int* rowptr = csum + 256;                                // 50004
    int* cursor = rowptr + NNODES + 4;                       // 50000
    int* csr    = cursor + NNODES;                           // 800000
    u16* xb     = (u16*)(csr + NEDGES);                      // N*128
    u16* W1p    = xb + (size_t)NNODES * FIN;                 // 32768
    u16* W2p    = W1p + 32768;                               // 16384
    u16* h1b    = W2p + 16384;                               // N*256
    u16* h1rb   = h1b + (size_t)NNODES * F1;                 // N*256
    u16* h2b    = h1rb + (size_t)NNODES * F1;                // N*64
    float* as1  = (float*)(h2b + (size_t)NNODES * HIDN);     // N*4
    float* ad1  = as1 + (size_t)NNODES * 4;                  // N*4
    float* as2  = ad1 + (size_t)NNODES * 4;                  // N
    float* ad2  = as2 + NNODES;                              // N
    float* hf   = ad2 + NNODES;                              // N*64
    float* scores = hf + (size_t)NNODES * HIDN;              // N
    float* stop_scores = scores + NNODES;                    // G
    size_t total = (char*)(stop_scores + GG) - (char*)d_ws;
    if (total > ws_size) return;

    auto cdiv = [](long long a, long long b) { return (int)((a + b - 1) / b); };

    hipMemsetAsync(d_ws, 0, zbytes, stream);

    // CSR build (dst-bucketed src ids) — parallel 3-phase scan
    hist_k<<<cdiv(NEDGES, 256), 256, 0, stream>>>(dstp, deg);
    chunksum_k<<<NCHUNK, 256, 0, stream>>>(deg, csum);
    chunkscan_k<<<1, 256, 0, stream>>>(csum);
    expand_k<<<NCHUNK, 256, 0, stream>>>(deg, csum, rowptr, cursor);
    scatter_k<<<cdiv(NEDGES, 256), 256, 0, stream>>>(srcp, dstp, cursor, csr);

    // casts + weight packs
    cast_k<<<cdiv((long long)NNODES * FIN / 4, 256), 256, 0, stream>>>(x, xb, NNODES * FIN / 4);
    pack_k<<<cdiv(32768, 256), 256, 0, stream>>>(W1, W1p, FIN, F1);
    pack_k<<<cdiv(16384, 256), 256, 0, stream>>>(W2, W2p, F1, HIDN);

    // layer 1
    gemm_mfma<4><<<dim3(cdiv(NNODES, 64), 1), 256, 0, stream>>>(xb, W1p, h1b, NNODES, FIN, F1);
    attdots1<<<cdiv((long long)NNODES * NHEADS, 256), 256, 0, stream>>>(h1b, att_s1, att_d1, as1, ad1);
    gagg1<<<cdiv(NNODES, 4), 256, 0, stream>>>(rowptr, csr, as1, ad1, h1b, b1, h1rb);

    // layer 2
    gemm_mfma<1><<<dim3(cdiv(NNODES, 64), 1), 256, 0, stream>>>(h1rb, W2p, h2b, NNODES, F1, HIDN);
    attdots2<<<cdiv(NNODES, 256), 256, 0, stream>>>(h2b, att_s2, att_d2, as2, ad2);
    gagg2<<<cdiv(NNODES, 4), 256, 0, stream>>>(rowptr, csr, as2, ad2, h2b, b2, hf);

    // heads
    scores_k<<<cdiv(NNODES, 256), 256, 0, stream>>>(hf, action_w, action_b, scores);
    ctx_k<<<GG, 64, 0, stream>>>(hf, cur_nodes, cur_counts, stop_w, stop_b, stop_scores, gmaxkey);
    redmax_k<<<dim3(64, GG), 256, 0, stream>>>(scores, masks, gmaxkey);
    redsum_k<<<dim3(64, GG), 256, 0, stream>>>(scores, masks, gmaxkey, stop_scores, gsum);
    write_k<<<dim3(cdiv(NNODES + 1, 256), GG), 256, 0, stream>>>(scores, masks, gmaxkey, gsum,
                                                                 stop_scores, cur_counts, out);
}

// Round 7
// 360.498 us; speedup vs baseline: 11.0530x; 1.2102x over previous
//
#include <hip/hip_runtime.h>
#include <hip/hip_runtime_api.h>

#define NNODES 50000
#define NEDGES 800000
#define GG 32
#define KCUR 16
#define FIN 128
#define HIDN 64
#define NHEADS 4
#define F1 256          // NHEADS*HIDN
#define NCHUNK 196      // ceil(NNODES/256)

typedef unsigned short u16;
typedef unsigned char u8;
typedef short bf8 __attribute__((ext_vector_type(8)));    // 8 bf16 in 4 VGPRs
typedef float f32x4 __attribute__((ext_vector_type(4)));

// ---- bf16 helpers ----
__device__ __forceinline__ u16 f2bf(float f) {
    unsigned u = __float_as_uint(f);
    return (u16)((u + 0x7fffu + ((u >> 16) & 1u)) >> 16);   // RNE
}
__device__ __forceinline__ float bf2f(u16 h) {
    return __uint_as_float(((unsigned)h) << 16);
}
__device__ __forceinline__ float lrelu(float x) { return x > 0.f ? x : 0.2f * x; }
// fp8 e4m3 HW converts
__device__ __forceinline__ unsigned pk4fp8(float a, float b, float c, float d) {
    unsigned u = __builtin_amdgcn_cvt_pk_fp8_f32(a, b, 0u, false);
    u = __builtin_amdgcn_cvt_pk_fp8_f32(c, d, u, true);
    return u;
}
template<int SEL>
__device__ __forceinline__ float fp8f(unsigned v) {
    return __builtin_amdgcn_cvt_f32_fp8(v, SEL);   // SEL must be compile-time const
}

// ---------------- pack W[K][N] fp32 -> bf16 MFMA fragment order (both weights) --
// Wp[((t*S + s)*64 + l)*8 + j] = W[s*32 + (l>>4)*8 + j][t*16 + (l&15)]
__global__ __launch_bounds__(256)
void pack_k(const float* __restrict__ W1, const float* __restrict__ W2,
            u16* __restrict__ W1p, u16* __restrict__ W2p)
{
    int idx = blockIdx.x * 256 + threadIdx.x;
    const float* src; u16* dst; int S, N, li;
    if (idx < 32768) { src = W1; dst = W1p; S = FIN / 32; N = F1; li = idx; }
    else if (idx < 49152) { src = W2; dst = W2p; S = F1 / 32; N = HIDN; li = idx - 32768; }
    else return;
    int j = li & 7, l = (li >> 3) & 63, rest = li >> 9;
    int s = rest % S, t = rest / S;
    int k = s * 32 + (l >> 4) * 8 + j;
    int n = t * 16 + (l & 15);
    dst[li] = f2bf(src[(size_t)k * N + n]);
}

// ---------------- CSR build ----------------
__global__ __launch_bounds__(256)
void hist_k(const int* __restrict__ dst, int* __restrict__ deg)
{
    int e = blockIdx.x * 256 + threadIdx.x;
    if (e >= NEDGES) return;
    atomicAdd(&deg[dst[e]], 1);
}

__global__ __launch_bounds__(256)
void chunksum_k(const int* __restrict__ deg, int* __restrict__ csum)
{
    __shared__ int ws[4];
    int i = blockIdx.x * 256 + threadIdx.x;
    int v = (i < NNODES) ? deg[i] : 0;
#pragma unroll
    for (int o = 32; o; o >>= 1) v += __shfl_down(v, o);
    if ((threadIdx.x & 63) == 0) ws[threadIdx.x >> 6] = v;
    __syncthreads();
    if (threadIdx.x == 0) csum[blockIdx.x] = ws[0] + ws[1] + ws[2] + ws[3];
}

// expand with fused chunk-offset computation (sum of csum[0..bx))
__global__ __launch_bounds__(256)
void expand_k(const int* __restrict__ deg, const int* __restrict__ csum,
              int* __restrict__ rowptr, int* __restrict__ cursor)
{
    __shared__ int ws[4], ws2[4];
    __shared__ int boff;
    int tid = threadIdx.x, lane = tid & 63, wid = tid >> 6;
    int v0 = (tid < blockIdx.x) ? csum[tid] : 0;    // blockIdx.x <= 195 < 256
#pragma unroll
    for (int o = 32; o; o >>= 1) v0 += __shfl_down(v0, o);
    if (lane == 0) ws[wid] = v0;
    __syncthreads();
    if (tid == 0) boff = ws[0] + ws[1] + ws[2] + ws[3];
    __syncthreads();
    int i = blockIdx.x * 256 + tid;
    int v = (i < NNODES) ? deg[i] : 0;
    int x = v;
#pragma unroll
    for (int o = 1; o < 64; o <<= 1) {
        int y = __shfl_up(x, o);
        if (lane >= o) x += y;
    }
    if (lane == 63) ws2[wid] = x;
    __syncthreads();
    int off = boff;
    for (int w = 0; w < wid; w++) off += ws2[w];
    int excl = off + x - v;
    if (i < NNODES) { rowptr[i] = excl; cursor[i] = excl; }
    if (i == 0) rowptr[NNODES] = NEDGES;
}

__global__ __launch_bounds__(256)
void scatter_k(const int* __restrict__ src, const int* __restrict__ dst,
               int* __restrict__ cursor, int* __restrict__ csr)
{
    int e = blockIdx.x * 256 + threadIdx.x;
    if (e >= NEDGES) return;
    int d = dst[e];
    int pos = atomicAdd(&cursor[d], 1);
    csr[pos] = src[e];
}

// ---------------- GEMM1: h1 = x @ W1 (fp32 in, fp8 out) + fused att dots ------
// Swapped-operand MFMA: D = Wp·Xp = (X·W)^T per tile, so each lane holds 4
// consecutive output channels for one node -> one u32 fp8 store.
__global__ __launch_bounds__(256)
void gemm1_k(const float* __restrict__ X, const u16* __restrict__ Bp,
             const float* __restrict__ att_s, const float* __restrict__ att_d,
             u8* __restrict__ h1f8, float* __restrict__ as1, float* __restrict__ ad1)
{
    const int S = FIN / 32;  // 4
    int lane = threadIdx.x & 63, w = threadIdx.x >> 6;
    int m0 = blockIdx.x * 64;
    int row_in = lane & 15, kq = lane >> 4;
    f32x4 acc[4][4];
#pragma unroll
    for (int r = 0; r < 4; r++)
#pragma unroll
        for (int tt = 0; tt < 4; tt++) acc[r][tt] = (f32x4){0.f, 0.f, 0.f, 0.f};
    int R = (NNODES - m0) >> 4; if (R > 4) R = 4;

    for (int s = 0; s < S; s++) {
        bf8 bfrag[4];
#pragma unroll
        for (int tt = 0; tt < 4; tt++) {
            int t = w * 4 + tt;
            bfrag[tt] = *(const bf8*)(Bp + (((size_t)t * S + s) * 64 + lane) * 8);
        }
        int kb = s * 32 + kq * 8;
        bf8 af[4];
#pragma unroll
        for (int r = 0; r < 4; r++)
            if (r < R) {
                const float* xp = X + (size_t)(m0 + r * 16 + row_in) * FIN + kb;
                float4 x0 = *(const float4*)xp;
                float4 x1 = *(const float4*)(xp + 4);
                bf8 a;
                a[0] = (short)f2bf(x0.x); a[1] = (short)f2bf(x0.y);
                a[2] = (short)f2bf(x0.z); a[3] = (short)f2bf(x0.w);
                a[4] = (short)f2bf(x1.x); a[5] = (short)f2bf(x1.y);
                a[6] = (short)f2bf(x1.z); a[7] = (short)f2bf(x1.w);
                af[r] = a;
            }
#pragma unroll
        for (int r = 0; r < 4; r++)
            if (r < R)
#pragma unroll
                for (int tt = 0; tt < 4; tt++)
                    acc[r][tt] = __builtin_amdgcn_mfma_f32_16x16x32_bf16(bfrag[tt], af[r], acc[r][tt], 0, 0, 0);
    }
    // epilogue: fp8 store + fused attention dots (head = w)
    float attS[16], attD[16];
#pragma unroll
    for (int tt = 0; tt < 4; tt++)
#pragma unroll
        for (int v = 0; v < 4; v++) {
            attS[tt * 4 + v] = att_s[w * 64 + tt * 16 + kq * 4 + v];
            attD[tt * 4 + v] = att_d[w * 64 + tt * 16 + kq * 4 + v];
        }
#pragma unroll
    for (int r = 0; r < 4; r++) {
        if (r >= R) break;
        int node = m0 + r * 16 + row_in;
        float pa = 0.f, pd = 0.f;
#pragma unroll
        for (int tt = 0; tt < 4; tt++) {
            unsigned u = pk4fp8(acc[r][tt][0], acc[r][tt][1], acc[r][tt][2], acc[r][tt][3]);
            *(unsigned*)(h1f8 + (size_t)node * F1 + (w * 4 + tt) * 16 + kq * 4) = u;
#pragma unroll
            for (int v = 0; v < 4; v++) {
                pa = fmaf(acc[r][tt][v], attS[tt * 4 + v], pa);
                pd = fmaf(acc[r][tt][v], attD[tt * 4 + v], pd);
            }
        }
        pa += __shfl_xor(pa, 16); pa += __shfl_xor(pa, 32);
        pd += __shfl_xor(pd, 16); pd += __shfl_xor(pd, 32);
        if (kq == 0) { as1[node * 4 + w] = pa; ad1[node * 4 + w] = pd; }
    }
}

// ---------------- layer-1 gather aggregation (fp8 gather, bf16 out) ------------
__global__ __launch_bounds__(256)
void gagg1(const int* __restrict__ rowptr, const int* __restrict__ csr,
           const float* __restrict__ as1, const float* __restrict__ ad1,
           const u8* __restrict__ h1f8, const float* __restrict__ b1,
           u16* __restrict__ outp)
{
    int wid = threadIdx.x >> 6, lane = threadIdx.x & 63;
    int d = blockIdx.x * 4 + wid;
    if (d >= NNODES) return;
    int beg = rowptr[d];
    int tot = rowptr[d + 1] - beg + 1;     // + self loop
    int half = lane >> 5;
    int l31 = lane & 31;
    int h = l31 >> 3;
    int c0 = l31 << 3;
    float adh = ad1[d * 4 + h];
    float den = 0.f;
    float acc[8];
#pragma unroll
    for (int j = 0; j < 8; j++) acc[j] = 0.f;

    for (int p = half; p < tot; p += 2) {
        int s = (p == 0) ? d : csr[beg + p - 1];
        float ex = __expf(lrelu(as1[s * 4 + h] + adh));
        den += ex;
        uint2 hv = *(const uint2*)(h1f8 + (size_t)s * F1 + c0);
        acc[0] = fmaf(ex, fp8f<0>(hv.x), acc[0]);
        acc[1] = fmaf(ex, fp8f<1>(hv.x), acc[1]);
        acc[2] = fmaf(ex, fp8f<2>(hv.x), acc[2]);
        acc[3] = fmaf(ex, fp8f<3>(hv.x), acc[3]);
        acc[4] = fmaf(ex, fp8f<0>(hv.y), acc[4]);
        acc[5] = fmaf(ex, fp8f<1>(hv.y), acc[5]);
        acc[6] = fmaf(ex, fp8f<2>(hv.y), acc[6]);
        acc[7] = fmaf(ex, fp8f<3>(hv.y), acc[7]);
    }
    den += __shfl_xor(den, 32);
#pragma unroll
    for (int j = 0; j < 8; j++) acc[j] += __shfl_xor(acc[j], 32);

    if (lane < 32) {
        float rden = 1.f / den;
        float4 blo = *(const float4*)(b1 + c0);
        float4 bhi = *(const float4*)(b1 + c0 + 4);
        float bb[8] = {blo.x, blo.y, blo.z, blo.w, bhi.x, bhi.y, bhi.z, bhi.w};
        bf8 o;
#pragma unroll
        for (int j = 0; j < 8; j++)
            o[j] = (short)f2bf(fmaxf(fmaf(acc[j], rden, bb[j]), 0.f));
        *(bf8*)(outp + (size_t)d * F1 + c0) = o;
    }
}

// ---------------- GEMM2: h2 = h1r @ W2 (bf16 in, fp8 out) + fused att dots ----
__global__ __launch_bounds__(256)
void gemm2_k(const u16* __restrict__ A, const u16* __restrict__ Bp,
             const float* __restrict__ att_s, const float* __restrict__ att_d,
             u8* __restrict__ h2f8, float* __restrict__ as2, float* __restrict__ ad2)
{
    const int S = F1 / 32;   // 8
    __shared__ float asl[4][64], adl[4][64];
    int lane = threadIdx.x & 63, w = threadIdx.x >> 6;
    int m0 = blockIdx.x * 64;
    int row_in = lane & 15, kq = lane >> 4;
    f32x4 acc[4];
#pragma unroll
    for (int r = 0; r < 4; r++) acc[r] = (f32x4){0.f, 0.f, 0.f, 0.f};
    int R = (NNODES - m0) >> 4; if (R > 4) R = 4;

    for (int s = 0; s < S; s++) {
        bf8 bfrag = *(const bf8*)(Bp + (((size_t)w * S + s) * 64 + lane) * 8);
        int kb = s * 32 + kq * 8;
        bf8 af[4];
#pragma unroll
        for (int r = 0; r < 4; r++)
            if (r < R) af[r] = *(const bf8*)(A + (size_t)(m0 + r * 16 + row_in) * F1 + kb);
#pragma unroll
        for (int r = 0; r < 4; r++)
            if (r < R)
                acc[r] = __builtin_amdgcn_mfma_f32_16x16x32_bf16(bfrag, af[r], acc[r], 0, 0, 0);
    }
    float attS[4], attD[4];
#pragma unroll
    for (int v = 0; v < 4; v++) {
        attS[v] = att_s[w * 16 + kq * 4 + v];
        attD[v] = att_d[w * 16 + kq * 4 + v];
    }
#pragma unroll
    for (int r = 0; r < 4; r++) {
        if (r >= R) break;
        int node = m0 + r * 16 + row_in;
        unsigned u = pk4fp8(acc[r][0], acc[r][1], acc[r][2], acc[r][3]);
        *(unsigned*)(h2f8 + (size_t)node * HIDN + w * 16 + kq * 4) = u;
        float pa = 0.f, pd = 0.f;
#pragma unroll
        for (int v = 0; v < 4; v++) {
            pa = fmaf(acc[r][v], attS[v], pa);
            pd = fmaf(acc[r][v], attD[v], pd);
        }
        pa += __shfl_xor(pa, 16); pa += __shfl_xor(pa, 32);
        pd += __shfl_xor(pd, 16); pd += __shfl_xor(pd, 32);
        if (kq == 0) { asl[w][r * 16 + row_in] = pa; adl[w][r * 16 + row_in] = pd; }
    }
    __syncthreads();
    int tid = threadIdx.x;
    if (tid < R * 16) {
        as2[m0 + tid] = asl[0][tid] + asl[1][tid] + asl[2][tid] + asl[3][tid];
        ad2[m0 + tid] = adl[0][tid] + adl[1][tid] + adl[2][tid] + adl[3][tid];
    }
}

// ---------------- layer-2 gather aggregation (fp8) + fused node score ---------
__global__ __launch_bounds__(256)
void gagg2(const int* __restrict__ rowptr, const int* __restrict__ csr,
           const float* __restrict__ as2, const float* __restrict__ ad2,
           const u8* __restrict__ h2f8, const float* __restrict__ b2,
           const float* __restrict__ aw, const float* __restrict__ ab,
           float* __restrict__ outp, float* __restrict__ scores)
{
    int wid = threadIdx.x >> 6, lane = threadIdx.x & 63;
    int d = blockIdx.x * 4 + wid;
    if (d >= NNODES) return;
    int beg = rowptr[d];
    int tot = rowptr[d + 1] - beg + 1;
    int q = lane >> 4;
    int c0 = (lane & 15) << 2;
    float ads = ad2[d];
    float den = 0.f;
    float a0 = 0.f, a1 = 0.f, a2 = 0.f, a3 = 0.f;

    for (int p = q; p < tot; p += 4) {
        int s = (p == 0) ? d : csr[beg + p - 1];
        float ex = __expf(lrelu(as2[s] + ads));
        den += ex;
        unsigned hv = *(const unsigned*)(h2f8 + (size_t)s * HIDN + c0);
        a0 = fmaf(ex, fp8f<0>(hv), a0);
        a1 = fmaf(ex, fp8f<1>(hv), a1);
        a2 = fmaf(ex, fp8f<2>(hv), a2);
        a3 = fmaf(ex, fp8f<3>(hv), a3);
    }
    den += __shfl_xor(den, 16);  a0 += __shfl_xor(a0, 16);
    a1 += __shfl_xor(a1, 16);    a2 += __shfl_xor(a2, 16);
    a3 += __shfl_xor(a3, 16);
    den += __shfl_xor(den, 32);  a0 += __shfl_xor(a0, 32);
    a1 += __shfl_xor(a1, 32);    a2 += __shfl_xor(a2, 32);
    a3 += __shfl_xor(a3, 32);

    float rden = 1.f / den;
    float4 bb = *(const float4*)(b2 + c0);
    float o0 = fmaf(a0, rden, bb.x);
    float o1 = fmaf(a1, rden, bb.y);
    float o2 = fmaf(a2, rden, bb.z);
    float o3 = fmaf(a3, rden, bb.w);
    if (lane < 16) {
        float4 o = make_float4(o0, o1, o2, o3);
        *(float4*)(outp + (size_t)d * HIDN + c0) = o;
    }
    // fused node score = tanh(hf . action_w + action_b)
    float p_ = o0 * aw[c0] + o1 * aw[c0 + 1] + o2 * aw[c0 + 2] + o3 * aw[c0 + 3];
    p_ += __shfl_xor(p_, 1); p_ += __shfl_xor(p_, 2);
    p_ += __shfl_xor(p_, 4); p_ += __shfl_xor(p_, 8);
    if (lane == 0) scores[d] = tanhf(p_ + ab[0]);
}

// ---------------- per-graph masked online-softmax partials --------------------
__global__ __launch_bounds__(256)
void partials_k(const float* __restrict__ scores, const int* __restrict__ masks,
                float* __restrict__ pmax, float* __restrict__ psum)
{
    __shared__ float lm[4], ls[4];
    int g = blockIdx.y;
    float m = -3.0e38f, s = 0.f;
    for (int n = blockIdx.x * 256 + threadIdx.x; n < NNODES; n += gridDim.x * 256) {
        if (masks[(size_t)g * NNODES + n]) {
            float v = scores[n];
            if (v > m) { s = s * __expf(m - v) + 1.f; m = v; }
            else s += __expf(v - m);
        }
    }
#pragma unroll
    for (int o = 1; o < 64; o <<= 1) {
        float om = __shfl_xor(m, o), os = __shfl_xor(s, o);
        float M = fmaxf(m, om);
        s = s * __expf(m - M) + os * __expf(om - M);
        m = M;
    }
    if ((threadIdx.x & 63) == 0) { lm[threadIdx.x >> 6] = m; ls[threadIdx.x >> 6] = s; }
    __syncthreads();
    if (threadIdx.x == 0) {
        float M = m, S = s;
        for (int w_ = 1; w_ < 4; w_++) {
            float M2 = fmaxf(M, lm[w_]);
            S = S * __expf(M - M2) + ls[w_] * __expf(lm[w_] - M2);
            M = M2;
        }
        pmax[g * 64 + blockIdx.x] = M;
        psum[g * 64 + blockIdx.x] = S;
    }
}

// ---------------- combine: ctx pooling + stop score + merge partials ----------
__global__ __launch_bounds__(64)
void combine_k(const float* __restrict__ hf, const int* __restrict__ cur_nodes,
               const int* __restrict__ cur_counts, const float* __restrict__ sw,
               const float* __restrict__ sb,
               const float* __restrict__ pmax, const float* __restrict__ psum,
               float* __restrict__ gmax, float* __restrict__ gsum,
               float* __restrict__ stops)
{
    int g = blockIdx.x, tid = threadIdx.x;
    int cnt = cur_counts[g];
    float s = 0.f;
    for (int k = 0; k < KCUR; k++)
        if (k < cnt) s += hf[(size_t)cur_nodes[g * KCUR + k] * HIDN + tid];
    float ctx = s / (float)(cnt > 1 ? cnt : 1);
    float p = ctx * sw[tid];
#pragma unroll
    for (int o = 1; o < 64; o <<= 1) p += __shfl_xor(p, o);
    float stop = tanhf(p + sb[0]);

    float m = pmax[g * 64 + tid], sm = psum[g * 64 + tid];
#pragma unroll
    for (int o = 1; o < 64; o <<= 1) {
        float om = __shfl_xor(m, o), os = __shfl_xor(sm, o);
        float M = fmaxf(m, om);
        sm = sm * __expf(m - M) + os * __expf(om - M);
        m = M;
    }
    if (tid == 0) {
        float M2 = fmaxf(m, stop);
        float S2 = sm * __expf(m - M2) + __expf(stop - M2);
        gmax[g] = M2; gsum[g] = S2; stops[g] = stop;
    }
}

// ---------------- final probability write ----------------
__global__ __launch_bounds__(256)
void write_k(const float* __restrict__ scores, const int* __restrict__ masks,
             const float* __restrict__ gmax, const float* __restrict__ gsum,
             const float* __restrict__ stops, const int* __restrict__ cur_counts,
             float* __restrict__ out)
{
    int g = blockIdx.y;
    int j = blockIdx.x * 256 + threadIdx.x;
    if (j > NNODES) return;
    float v;
    if (cur_counts[g] == 0) {
        v = (j == NNODES) ? 1.f : 0.f;
    } else {
        float m = gmax[g];
        float Z = gsum[g];
        if (j == NNODES) v = __expf(stops[g] - m) / Z;
        else v = masks[(size_t)g * NNODES + j] ? __expf(scores[j] - m) / Z : 0.f;
    }
    out[(size_t)g * (NNODES + 1) + j] = v;
}

extern "C" void kernel_launch(void* const* d_in, const int* in_sizes, int n_in,
                              void* d_out, int out_size, void* d_ws, size_t ws_size,
                              hipStream_t stream) {
    const float* x        = (const float*)d_in[0];
    const int* ei         = (const int*)d_in[1];
    const int* cur_nodes  = (const int*)d_in[2];
    const int* cur_counts = (const int*)d_in[3];
    const int* masks      = (const int*)d_in[4];
    const float* W1       = (const float*)d_in[5];
    const float* att_s1   = (const float*)d_in[6];
    const float* att_d1   = (const float*)d_in[7];
    const float* b1       = (const float*)d_in[8];
    const float* W2       = (const float*)d_in[9];
    const float* att_s2   = (const float*)d_in[10];
    const float* att_d2   = (const float*)d_in[11];
    const float* b2       = (const float*)d_in[12];
    const float* action_w = (const float*)d_in[13];
    const float* action_b = (const float*)d_in[14];
    const float* stop_w   = (const float*)d_in[15];
    const float* stop_b   = (const float*)d_in[16];
    float* out = (float*)d_out;

    const int* srcp = ei;
    const int* dstp = ei + NEDGES;

    // ---- workspace layout ----
    int* deg = (int*)d_ws;                                   // 50000 (zeroed)
    char* zend = (char*)(deg + NNODES);
    size_t zbytes = zend - (char*)d_ws;
    int* csum   = (int*)zend;                                // 256
    int* rowptr = csum + 256;                                // 50001 (+3 pad)
    int* cursor = rowptr + NNODES + 4;                       // 50000
    int* csr    = cursor + NNODES;                           // 800000
    u16* W1p    = (u16*)(csr + NEDGES);                      // 32768
    u16* W2p    = W1p + 32768;                               // 16384
    u8*  h1f8   = (u8*)(W2p + 16384);                        // N*256
    u16* h1rb   = (u16*)(h1f8 + (size_t)NNODES * F1);        // N*256
    u8*  h2f8   = (u8*)(h1rb + (size_t)NNODES * F1);         // N*64
    float* as1  = (float*)(h2f8 + (size_t)NNODES * HIDN);    // N*4
    float* ad1  = as1 + (size_t)NNODES * 4;                  // N*4
    float* as2  = ad1 + (size_t)NNODES * 4;                  // N
    float* ad2  = as2 + NNODES;                              // N
    float* hf   = ad2 + NNODES;                              // N*64
    float* scores = hf + (size_t)NNODES * HIDN;              // N
    float* stops  = scores + NNODES;                         // G
    float* pmax = stops + GG;                                // G*64
    float* psum = pmax + GG * 64;                            // G*64
    float* gmax = psum + GG * 64;                            // G
    float* gsum = gmax + GG;                                 // G
    size_t total = (char*)(gsum + GG) - (char*)d_ws;
    if (total > ws_size) return;

    auto cdiv = [](long long a, long long b) { return (int)((a + b - 1) / b); };

    (void)hipMemsetAsync(deg, 0, zbytes, stream);

    // CSR build
    hist_k<<<cdiv(NEDGES, 256), 256, 0, stream>>>(dstp, deg);
    chunksum_k<<<NCHUNK, 256, 0, stream>>>(deg, csum);
    expand_k<<<NCHUNK, 256, 0, stream>>>(deg, csum, rowptr, cursor);
    scatter_k<<<cdiv(NEDGES, 256), 256, 0, stream>>>(srcp, dstp, cursor, csr);

    // weight packs (both in one launch)
    pack_k<<<192, 256, 0, stream>>>(W1, W2, W1p, W2p);

    // layer 1
    gemm1_k<<<cdiv(NNODES, 64), 256, 0, stream>>>(x, W1p, att_s1, att_d1, h1f8, as1, ad1);
    gagg1<<<cdiv(NNODES, 4), 256, 0, stream>>>(rowptr, csr, as1, ad1, h1f8, b1, h1rb);

    // layer 2
    gemm2_k<<<cdiv(NNODES, 64), 256, 0, stream>>>(h1rb, W2p, att_s2, att_d2, h2f8, as2, ad2);
    gagg2<<<cdiv(NNODES, 4), 256, 0, stream>>>(rowptr, csr, as2, ad2, h2f8, b2,
                                               action_w, action_b, hf, scores);

    // heads / softmax
    partials_k<<<dim3(64, GG), 256, 0, stream>>>(scores, masks, pmax, psum);
    combine_k<<<GG, 64, 0, stream>>>(hf, cur_nodes, cur_counts, stop_w, stop_b,
                                     pmax, psum, gmax, gsum, stops);
    write_k<<<dim3(cdiv(NNODES + 1, 256), GG), 256, 0, stream>>>(scores, masks, gmax, gsum,
                                                                 stops, cur_counts, out);
}